// Round 5
// baseline (641.785 us; speedup 1.0000x reference)
//
#include <hip/hip_runtime.h>
#include <hip/hip_bf16.h>

#define TDIM 256
#define VDIM 25
#define CDIM 64
#define BDIM 32
#define EPSV 1e-5f

// ws layout
#define XM_OFF     0            // 51200 floats
#define LOSSP_OFF  51200        // 3072 floats
#define WPACK_BYTE 217088       // 96 packs * 9216 shorts (bf16 z B-frags)
#define WL_SH      9216         // shorts per (b,s): 18 kvh * 4 g * 16 col * 8
#define W3P_BYTE   (WPACK_BYTE + 96 * WL_SH * 2)  // 1986560; 3s*4096 shorts

typedef short s4v __attribute__((ext_vector_type(4)));
typedef short s8v __attribute__((ext_vector_type(8)));
typedef float f4v __attribute__((ext_vector_type(4)));

__device__ __forceinline__ unsigned f2bf(float f) {
  __hip_bfloat16 h = __float2bfloat16(f);
  return (unsigned)__builtin_bit_cast(unsigned short, h);
}
__device__ __forceinline__ float bf2f(unsigned short u) {
  unsigned v = ((unsigned)u) << 16;
  return __builtin_bit_cast(float, v);
}

// ---------------- Kernel 1: xm[b,c,v] = mean over T ----------------
__global__ __launch_bounds__(256) void kmean(const float* __restrict__ x,
                                             float* __restrict__ ws) {
  int bc = blockIdx.x;
  int tid = threadIdx.x;
  int vl = tid & 31, tr = tid >> 5;
  float acc = 0.f;
  if (vl < VDIM) {
    const float* p = x + (size_t)bc * TDIM * VDIM + vl;
    for (int t = tr; t < TDIM; t += 8) acc += p[(size_t)t * VDIM];
  }
  __shared__ float red[256];
  red[tid] = acc;
  __syncthreads();
  if (tr == 0 && vl < VDIM) {
    float s = 0.f;
    for (int r = 0; r < 8; ++r) s += red[r * 32 + vl];
    ws[XM_OFF + bc * VDIM + vl] = s * (1.f / 256.f);
  }
}

// ---------------- Kernel 2: dynamic weights -> packed bf16 fragments ----------------
__global__ __launch_bounds__(256) void kadj(const float* __restrict__ A,
                                            const float* __restrict__ alpha,
                                            const float* __restrict__ W1,
                                            const float* __restrict__ b1,
                                            const float* __restrict__ W2,
                                            const float* __restrict__ b2,
                                            const float* __restrict__ W3,
                                            float* __restrict__ ws,
                                            float* __restrict__ out_ridge) {
  int s = blockIdx.x >> 5, b = blockIdx.x & 31;
  int tid = threadIdx.x;
  __shared__ float xm[CDIM * VDIM];
  __shared__ float w1l[9 * CDIM], w2l[9 * CDIM];
  __shared__ float b1l[9], b2l[9];
  __shared__ float x1l[9 * VDIM], x2l[9 * VDIM];
  __shared__ float red[256];
  __shared__ float wsm[9 * VDIM * VDIM];   // w[k][v][i] f32

  for (int i = tid; i < CDIM * VDIM; i += 256) xm[i] = ws[XM_OFF + b * CDIM * VDIM + i];
  for (int i = tid; i < 9 * CDIM; i += 256) {
    w1l[i] = W1[s * 9 * CDIM + i];
    w2l[i] = W2[s * 9 * CDIM + i];
  }
  if (tid < 9) { b1l[tid] = b1[s * 9 + tid]; b2l[tid] = b2[s * 9 + tid]; }
  __syncthreads();

  if (tid < 9 * VDIM) {
    int ts = tid / VDIM, v = tid % VDIM;
    float a1 = 0.f, a2 = 0.f;
    for (int c = 0; c < CDIM; ++c) {
      float xv = xm[c * VDIM + v];
      a1 = fmaf(xv, w1l[ts * CDIM + c], a1);
      a2 = fmaf(xv, w2l[ts * CDIM + c], a2);
    }
    x1l[tid] = a1 + b1l[ts];
    x2l[tid] = a2 + b2l[ts];
  }
  __syncthreads();

  float al = alpha[0];
  float rid = 0.f;
  for (int idx = tid; idx < 9 * VDIM * VDIM; idx += 256) {
    int k = idx / (VDIM * VDIM);
    int r = (idx / VDIM) % VDIM;   // v
    int q = idx % VDIM;            // i
    float adj = tanhf(x1l[k * VDIM + r] - x2l[k * VDIM + q]);
    rid += adj * adj;
    wsm[idx] = fmaf(adj, al, A[(s * VDIM + r) * VDIM + q]);
  }
  red[tid] = rid;
  __syncthreads();   // wsm + red complete

  // pack z B-frags: [kvh 18][g 4][col 16][n2*j4]; k-element = (lane>>4)*4+j
  {
    unsigned short* wp = (unsigned short*)((char*)ws + WPACK_BYTE) + (size_t)(b * 3 + s) * WL_SH;
    for (int idx = tid; idx < WL_SH; idx += 256) {
      int kvh = idx >> 9;
      int rem = idx & 511;
      int gg = rem >> 7;
      int e = rem & 127;
      int colv = e >> 3;
      int q = e & 7;
      int n = q >> 2, jj = q & 3;
      int k = kvh >> 1, vh = kvh & 1;
      int v = vh * 16 + gg * 4 + jj;
      int i = n * 16 + colv;
      float val = (v < VDIM && i < VDIM) ? wsm[(k * VDIM + v) * VDIM + i] : 0.f;
      wp[idx] = (unsigned short)f2bf(val);
    }
  }

  for (int st = 128; st > 0; st >>= 1) {
    if (tid < st) red[tid] += red[tid + st];
    __syncthreads();
  }
  if (tid == 0) out_ridge[s * BDIM + b] = red[0];

  // pack W3 A-frags: [s][p][mt][col16][g4][j4]; A[m=o][k=c_local], c = p*16+g*4+j
  if (b == 0) {
    unsigned short* w3p = (unsigned short*)((char*)ws + W3P_BYTE) + s * 4096;
    for (int idx = tid; idx < 4096; idx += 256) {
      int pm = idx >> 8;          // p*4+mt
      int p = pm >> 2, mt = pm & 3;
      int e = idx & 255;
      int colv = e >> 4, gg = (e >> 2) & 3, jj = e & 3;
      int o = mt * 16 + colv, c = p * 16 + gg * 4 + jj;
      w3p[idx] = (unsigned short)f2bf(W3[(s * CDIM + o) * CDIM + c]);
    }
  }
}

// ---------------- Kernel 3: all-MFMA fused z -> (loss, y) ----------------
// B-frags for z read DIRECTLY from global (L2-resident pack) — no wl LDS.
// xw: [c16][tp16] rows of 16 uints, v-granule (2u) stored at gv^(tp&7)  (conflict-free b64)
// zly: [n=t*32+i 256][18 shorts] (c-local 16)
__global__ __launch_bounds__(256, 4) void kmain(const float* __restrict__ x,
                                                const float* __restrict__ b3,
                                                const float* __restrict__ bng,
                                                const float* __restrict__ bnb,
                                                const float* __restrict__ bnm,
                                                const float* __restrict__ bnv,
                                                const float* __restrict__ ws,
                                                float* __restrict__ out,
                                                float* __restrict__ lossP) {
  const int tile = blockIdx.x;   // 0..31 (8 t per tile)
  const int b    = blockIdx.y;   // 0..31
  const int t0   = tile * 8;
  const int tid  = threadIdx.x;
  const int wid  = tid >> 6;
  const int lane = tid & 63;
  const int g    = lane >> 4;
  const int col  = lane & 15;
  const int w4   = wid * 4;

  __shared__ __align__(16) unsigned xw_u[4096];   // 16384 B
  __shared__ __align__(16) short zly[4608];       // 9216 B

  const unsigned short* wpack = (const unsigned short*)((const char*)ws + WPACK_BYTE);
  const unsigned short* w3p   = (const unsigned short*)((const char*)ws + W3P_BYTE);

  auto stage_xw = [&](int p) {
    int c_s = tid >> 4, r = tid & 15, slot = r & 7, th = r >> 3;
    const float* xsrc = x + (size_t)(b * 64 + p * 16 + c_s) * TDIM * VDIM;
#pragma unroll
    for (int m = 0; m < 8; ++m) {
      int tp = m * 2 + th;
      int gt = t0 - 8 + tp;
      float f0 = 0.f, f1 = 0.f, f2 = 0.f, f3 = 0.f;
      if (gt >= 0 && slot < 7) {
        const float* rp = xsrc + (size_t)gt * VDIM + slot * 4;
        if (slot < 6) { float4 q4 = *(const float4*)rp; f0 = q4.x; f1 = q4.y; f2 = q4.z; f3 = q4.w; }
        else f0 = rp[0];   // slot 6: only v=24 valid
      }
      unsigned lo = f2bf(f0) | (f2bf(f1) << 16);
      unsigned hi = f2bf(f2) | (f2bf(f3) << 16);
      int ua = (c_s * 16 + tp) * 16 + ((slot ^ (tp & 7)) << 1);
      xw_u[ua] = lo; xw_u[ua + 1] = hi;
    }
  };

  // z lane constants
  const int a_cc = col >> 3, a_t = col & 7;
  const int cl0 = w4 + a_cc, cl1 = w4 + 2 + a_cc;
  const unsigned short* bb_base = wpack + (size_t)(b * 3) * WL_SH + g * 128 + col * 8;

  f4v yacc[4][4];
#pragma unroll
  for (int i = 0; i < 4; ++i)
#pragma unroll
    for (int j = 0; j < 4; ++j) yacc[i][j] = (f4v){0.f, 0.f, 0.f, 0.f};
  float lossA[3] = {0.f, 0.f, 0.f};

  stage_xw(0);

  for (int p = 0; p < 4; ++p) {
#pragma unroll
    for (int s = 0; s < 3; ++s) {
      __syncthreads();   // BARRIER_A: prev y-reads of zly done; xw stage visible

      // y A-frags (global, L2-hot) — used after BARRIER_B
      const unsigned short* a3p = w3p + (size_t)((s * 4 + p) * 4) * 256 + col * 16 + g * 4;
      s4v a3_0 = *(const s4v*)(a3p);
      s4v a3_1 = *(const s4v*)(a3p + 256);
      s4v a3_2 = *(const s4v*)(a3p + 512);
      s4v a3_3 = *(const s4v*)(a3p + 768);

      const unsigned short* bs = bb_base + (size_t)s * WL_SH;

      // ---- z MFMA: 36 mfma per wave, B from global ----
      f4v za00 = {0.f,0.f,0.f,0.f}, za01 = {0.f,0.f,0.f,0.f};
      f4v za10 = {0.f,0.f,0.f,0.f}, za11 = {0.f,0.f,0.f,0.f};
#pragma unroll
      for (int k = 0; k < 9; ++k) {
        int tp = a_t + k;
        int x0 = (cl0 * 16 + tp) * 16;
        int x1 = (cl1 * 16 + tp) * 16;
        int msk = tp & 7;
#pragma unroll
        for (int vh = 0; vh < 2; ++vh) {
          int sw = ((vh * 4 + g) ^ msk) << 1;
          uint2 ua0 = *(const uint2*)&xw_u[x0 + sw];
          uint2 ua1 = *(const uint2*)&xw_u[x1 + sw];
          s4v a0 = __builtin_bit_cast(s4v, ua0);
          s4v a1 = __builtin_bit_cast(s4v, ua1);
          s8v bbv = *(const s8v*)(bs + (k * 2 + vh) * 512);
          s4v b0 = __builtin_shufflevector(bbv, bbv, 0, 1, 2, 3);
          s4v b1 = __builtin_shufflevector(bbv, bbv, 4, 5, 6, 7);
          za00 = __builtin_amdgcn_mfma_f32_16x16x16bf16_1k(a0, b0, za00, 0, 0, 0);
          za01 = __builtin_amdgcn_mfma_f32_16x16x16bf16_1k(a0, b1, za01, 0, 0, 0);
          za10 = __builtin_amdgcn_mfma_f32_16x16x16bf16_1k(a1, b0, za10, 0, 0, 0);
          za11 = __builtin_amdgcn_mfma_f32_16x16x16bf16_1k(a1, b1, za11, 0, 0, 0);
        }
      }

      // ---- loss + zly write ----
      const short* xw_s = (const short*)xw_u;
      float lp = 0.f;
#pragma unroll
      for (int mt = 0; mt < 2; ++mt) {
#pragma unroll
        for (int q = 0; q < 4; ++q) {
          int mrow = mt * 16 + g * 4 + q;
          int clz = w4 + (mrow >> 3);
          int t = mrow & 7;
          int tp = t + 8;
          int rowx = (clz * 16 + tp) * 32;
          int msk = tp & 7;
          float zv0 = (mt == 0) ? za00[q] : za10[q];
          {
            int i = col;
            float xf = bf2f((unsigned short)xw_s[rowx + (((i >> 2) ^ msk) << 2) + (i & 3)]);
            float d = zv0 - xf;
            lp = fmaf(d, d, lp);
            zly[(t * 32 + i) * 18 + clz] = (short)f2bf(zv0);
          }
          float zv1 = (mt == 0) ? za01[q] : za11[q];
          {
            int i = 16 + col;
            zly[(t * 32 + i) * 18 + clz] = (short)f2bf(zv1);
            if (i < VDIM) {
              float xf = bf2f((unsigned short)xw_s[rowx + (((i >> 2) ^ msk) << 2) + (i & 3)]);
              float d = zv1 - xf;
              lp = fmaf(d, d, lp);
            }
          }
        }
      }
      lossA[s] += lp;

      __syncthreads();   // BARRIER_B: zly ready; xw/zly reads of this phase done

      // ---- y MFMA: 16 per wave ----
      const unsigned* zly_u = (const unsigned*)zly;
#pragma unroll
      for (int nt = 0; nt < 4; ++nt) {
        int zo = ((w4 + nt) * 16 + col) * 9 + g * 2;
        uint2 uz; uz.x = zly_u[zo]; uz.y = zly_u[zo + 1];
        s4v bz = __builtin_bit_cast(s4v, uz);
        yacc[0][nt] = __builtin_amdgcn_mfma_f32_16x16x16bf16_1k(a3_0, bz, yacc[0][nt], 0, 0, 0);
        yacc[1][nt] = __builtin_amdgcn_mfma_f32_16x16x16bf16_1k(a3_1, bz, yacc[1][nt], 0, 0, 0);
        yacc[2][nt] = __builtin_amdgcn_mfma_f32_16x16x16bf16_1k(a3_2, bz, yacc[2][nt], 0, 0, 0);
        yacc[3][nt] = __builtin_amdgcn_mfma_f32_16x16x16bf16_1k(a3_3, bz, yacc[3][nt], 0, 0, 0);
      }

      // stage next c-panel (xw reads all complete; zly region untouched)
      if (s == 2 && p < 3) stage_xw(p + 1);
    }
  }

  __syncthreads();

  // ---- bn constants into zly scratch ----
  float* bnf = (float*)zly;
  if (tid < 64) {
    float inv = bng[tid] / sqrtf(bnv[tid] + EPSV);
    bnf[tid] = inv;
    bnf[64 + tid] = (b3[tid] + b3[64 + tid] + b3[128 + tid] - bnm[tid]) * inv + bnb[tid];
  }

  // ---- loss reduce (xw region as scratch) ----
  {
    float* redf = (float*)xw_u;
#pragma unroll
    for (int s = 0; s < 3; ++s) {
      __syncthreads();
      redf[tid] = lossA[s];
      __syncthreads();
      for (int st = 128; st > 0; st >>= 1) {
        if (tid < st) redf[tid] += redf[tid + st];
        __syncthreads();
      }
      if (tid == 0) lossP[(blockIdx.y * 32 + blockIdx.x) * 3 + s] = redf[0];
    }
    __syncthreads();
  }

  // ---- epilogue: y = relu(acc*inv + off + x) ----
#pragma unroll
  for (int nt = 0; nt < 4; ++nt) {
    int nIdx = (w4 + nt) * 16 + col;
    int t = nIdx >> 5, i = nIdx & 31;
    if (i < VDIM) {
      int gt = t0 + t;
#pragma unroll
      for (int mt = 0; mt < 4; ++mt) {
#pragma unroll
        for (int q = 0; q < 4; ++q) {
          int o = mt * 16 + g * 4 + q;
          size_t idx = ((size_t)(b * 64 + o) * TDIM + gt) * VDIM + i;
          float v = yacc[mt][nt][q] * bnf[o] + bnf[64 + o] + x[idx];
          out[idx] = fmaxf(v, 0.f);
        }
      }
    }
  }
}

// ---------------- Kernel 4: finalize loss ----------------
__global__ __launch_bounds__(256) void kfin(const float* __restrict__ lossP,
                                            float* __restrict__ out_loss) {
  __shared__ float red[256];
  int tid = threadIdx.x;
  for (int s = 0; s < 3; ++s) {
    float a = 0.f;
    for (int i = tid; i < 1024; i += 256) a += lossP[i * 3 + s];
    red[tid] = a;
    __syncthreads();
    for (int st = 128; st > 0; st >>= 1) {
      if (tid < st) red[tid] += red[tid + st];
      __syncthreads();
    }
    if (tid == 0) out_loss[s] = red[0] * (1.f / 13107200.f);
    __syncthreads();
  }
}

extern "C" void kernel_launch(void* const* d_in, const int* in_sizes, int n_in,
                              void* d_out, int out_size, void* d_ws, size_t ws_size,
                              hipStream_t stream) {
  (void)in_sizes; (void)n_in; (void)out_size; (void)ws_size;
  const float* x     = (const float*)d_in[0];
  const float* A     = (const float*)d_in[1];
  const float* alpha = (const float*)d_in[2];
  const float* W1    = (const float*)d_in[3];
  const float* b1    = (const float*)d_in[4];
  const float* W2    = (const float*)d_in[5];
  const float* b2    = (const float*)d_in[6];
  const float* W3    = (const float*)d_in[7];
  const float* b3    = (const float*)d_in[8];
  const float* bng   = (const float*)d_in[9];
  const float* bnb   = (const float*)d_in[10];
  const float* bnm   = (const float*)d_in[11];
  const float* bnv   = (const float*)d_in[12];
  float* out = (float*)d_out;
  float* ws  = (float*)d_ws;
  float* out_loss  = out + 13107200;
  float* out_ridge = out + 13107203;
  float* lossP = ws + LOSSP_OFF;

  kmean<<<2048, 256, 0, stream>>>(x, ws);
  kadj<<<96, 256, 0, stream>>>(A, alpha, W1, b1, W2, b2, W3, ws, out_ridge);
  kmain<<<dim3(32, 32), 256, 0, stream>>>(x, b3, bng, bnb, bnm, bnv, ws, out, lossP);
  kfin<<<1, 256, 0, stream>>>(lossP, out_loss);
}

// Round 6
// 576.293 us; speedup vs baseline: 1.1136x; 1.1136x over previous
//
#include <hip/hip_runtime.h>
#include <hip/hip_bf16.h>

#define TDIM 256
#define VDIM 25
#define CDIM 64
#define BDIM 32
#define EPSV 1e-5f

// ws layout
#define XM_OFF     0            // 51200 floats
#define LOSSP_OFF  51200        // 6144 floats (2048 blocks * 3)
#define WPACK_BYTE 229376       // 96 packs * 9216 shorts (bf16 z B-frags)
#define WL_SH      9216         // shorts per (b,s): 18 kvh * 4 g * 16 col * 8
#define W3P_BYTE   (WPACK_BYTE + 96 * WL_SH * 2)  // 1998848; 3s*4096 shorts

typedef short s4v __attribute__((ext_vector_type(4)));
typedef short s8v __attribute__((ext_vector_type(8)));
typedef float f4v __attribute__((ext_vector_type(4)));

__device__ __forceinline__ unsigned f2bf(float f) {
  __hip_bfloat16 h = __float2bfloat16(f);
  return (unsigned)__builtin_bit_cast(unsigned short, h);
}
__device__ __forceinline__ float bf2f(unsigned short u) {
  unsigned v = ((unsigned)u) << 16;
  return __builtin_bit_cast(float, v);
}

// ---------------- Kernel 1: xm[b,c,v] = mean over T ----------------
__global__ __launch_bounds__(256) void kmean(const float* __restrict__ x,
                                             float* __restrict__ ws) {
  int bc = blockIdx.x;
  int tid = threadIdx.x;
  int vl = tid & 31, tr = tid >> 5;
  float acc = 0.f;
  if (vl < VDIM) {
    const float* p = x + (size_t)bc * TDIM * VDIM + vl;
    for (int t = tr; t < TDIM; t += 8) acc += p[(size_t)t * VDIM];
  }
  __shared__ float red[256];
  red[tid] = acc;
  __syncthreads();
  if (tr == 0 && vl < VDIM) {
    float s = 0.f;
    for (int r = 0; r < 8; ++r) s += red[r * 32 + vl];
    ws[XM_OFF + bc * VDIM + vl] = s * (1.f / 256.f);
  }
}

// ---------------- Kernel 2: dynamic weights -> packed bf16 fragments ----------------
__global__ __launch_bounds__(256) void kadj(const float* __restrict__ A,
                                            const float* __restrict__ alpha,
                                            const float* __restrict__ W1,
                                            const float* __restrict__ b1,
                                            const float* __restrict__ W2,
                                            const float* __restrict__ b2,
                                            const float* __restrict__ W3,
                                            float* __restrict__ ws,
                                            float* __restrict__ out_ridge) {
  int s = blockIdx.x >> 5, b = blockIdx.x & 31;
  int tid = threadIdx.x;
  __shared__ float xm[CDIM * VDIM];
  __shared__ float w1l[9 * CDIM], w2l[9 * CDIM];
  __shared__ float b1l[9], b2l[9];
  __shared__ float x1l[9 * VDIM], x2l[9 * VDIM];
  __shared__ float red[256];
  __shared__ float wsm[9 * VDIM * VDIM];   // w[k][v][i] f32

  for (int i = tid; i < CDIM * VDIM; i += 256) xm[i] = ws[XM_OFF + b * CDIM * VDIM + i];
  for (int i = tid; i < 9 * CDIM; i += 256) {
    w1l[i] = W1[s * 9 * CDIM + i];
    w2l[i] = W2[s * 9 * CDIM + i];
  }
  if (tid < 9) { b1l[tid] = b1[s * 9 + tid]; b2l[tid] = b2[s * 9 + tid]; }
  __syncthreads();

  if (tid < 9 * VDIM) {
    int ts = tid / VDIM, v = tid % VDIM;
    float a1 = 0.f, a2 = 0.f;
    for (int c = 0; c < CDIM; ++c) {
      float xv = xm[c * VDIM + v];
      a1 = fmaf(xv, w1l[ts * CDIM + c], a1);
      a2 = fmaf(xv, w2l[ts * CDIM + c], a2);
    }
    x1l[tid] = a1 + b1l[ts];
    x2l[tid] = a2 + b2l[ts];
  }
  __syncthreads();

  float al = alpha[0];
  float rid = 0.f;
  for (int idx = tid; idx < 9 * VDIM * VDIM; idx += 256) {
    int k = idx / (VDIM * VDIM);
    int r = (idx / VDIM) % VDIM;   // v
    int q = idx % VDIM;            // i
    float adj = tanhf(x1l[k * VDIM + r] - x2l[k * VDIM + q]);
    rid += adj * adj;
    wsm[idx] = fmaf(adj, al, A[(s * VDIM + r) * VDIM + q]);
  }
  red[tid] = rid;
  __syncthreads();   // wsm + red complete

  // pack z B-frags: [kvh 18][g 4][col 16][n2*j4]; k-element = (lane>>4)*4+j
  {
    unsigned short* wp = (unsigned short*)((char*)ws + WPACK_BYTE) + (size_t)(b * 3 + s) * WL_SH;
    for (int idx = tid; idx < WL_SH; idx += 256) {
      int kvh = idx >> 9;
      int rem = idx & 511;
      int gg = rem >> 7;
      int e = rem & 127;
      int colv = e >> 3;
      int q = e & 7;
      int n = q >> 2, jj = q & 3;
      int k = kvh >> 1, vh = kvh & 1;
      int v = vh * 16 + gg * 4 + jj;
      int i = n * 16 + colv;
      float val = (v < VDIM && i < VDIM) ? wsm[(k * VDIM + v) * VDIM + i] : 0.f;
      wp[idx] = (unsigned short)f2bf(val);
    }
  }

  for (int st = 128; st > 0; st >>= 1) {
    if (tid < st) red[tid] += red[tid + st];
    __syncthreads();
  }
  if (tid == 0) out_ridge[s * BDIM + b] = red[0];

  // pack W3 A-frags: [s][p][mt][col16][g4][j4]; A[m=o][k=c_local], c = p*16+g*4+j
  if (b == 0) {
    unsigned short* w3p = (unsigned short*)((char*)ws + W3P_BYTE) + s * 4096;
    for (int idx = tid; idx < 4096; idx += 256) {
      int pm = idx >> 8;          // p*4+mt
      int p = pm >> 2, mt = pm & 3;
      int e = idx & 255;
      int colv = e >> 4, gg = (e >> 2) & 3, jj = e & 3;
      int o = mt * 16 + colv, c = p * 16 + gg * 4 + jj;
      w3p[idx] = (unsigned short)f2bf(W3[(s * CDIM + o) * CDIM + c]);
    }
  }
}

// ---------------- Kernel 3: all-MFMA fused z -> (loss, y), t-tile = 4 ----------------
// xw: [tp12][c16] rows of 16 uints; v-granule gv at (gv ^ ((tp+c)&7))  (<=2-way reads)
// zly: [n=t*32+i 128][18 shorts]; z B-frags direct from global (L2-resident)
__global__ __launch_bounds__(256, 4) void kmain(const float* __restrict__ x,
                                                const float* __restrict__ b3,
                                                const float* __restrict__ bng,
                                                const float* __restrict__ bnb,
                                                const float* __restrict__ bnm,
                                                const float* __restrict__ bnv,
                                                const float* __restrict__ ws,
                                                float* __restrict__ out,
                                                float* __restrict__ lossP) {
  const int id   = blockIdx.x;                      // 0..63
  const int tile = ((id & 7) << 3) | (id >> 3);     // XCD-contiguous t-chunks
  const int b    = blockIdx.y;
  const int t0   = tile * 4;
  const int tid  = threadIdx.x;
  const int wid  = tid >> 6;
  const int lane = tid & 63;
  const int g    = lane >> 4;
  const int col  = lane & 15;
  const int w4   = wid * 4;

  __shared__ __align__(16) unsigned xw_u[3072];   // 12288 B: [tp12][c16] x 16u
  __shared__ __align__(16) short zly[2304];       // 4608 B: [n128][18]
  __shared__ float bnf[128];

  if (tid < 64) {
    float inv = bng[tid] / sqrtf(bnv[tid] + EPSV);
    bnf[tid] = inv;
    bnf[64 + tid] = (b3[tid] + b3[64 + tid] + b3[128 + tid] - bnm[tid]) * inv + bnb[tid];
  }

  const unsigned short* wpack = (const unsigned short*)((const char*)ws + WPACK_BYTE);
  const unsigned short* w3p   = (const unsigned short*)((const char*)ws + W3P_BYTE);

  auto stage_xw = [&](int p) {
    int c_s = tid >> 4, r = tid & 15, slot = r & 7, th = r >> 3;
    const float* xsrc = x + (size_t)(b * 64 + p * 16 + c_s) * TDIM * VDIM;
#pragma unroll
    for (int m = 0; m < 6; ++m) {
      int tp = m * 2 + th;
      int gt = t0 - 8 + tp;
      float f0 = 0.f, f1 = 0.f, f2 = 0.f, f3 = 0.f;
      if (gt >= 0 && slot < 7) {
        const float* rp = xsrc + (size_t)gt * VDIM + slot * 4;
        if (slot < 6) { float4 q4 = *(const float4*)rp; f0 = q4.x; f1 = q4.y; f2 = q4.z; f3 = q4.w; }
        else f0 = rp[0];   // slot 6: only v=24 valid
      }
      unsigned lo = f2bf(f0) | (f2bf(f1) << 16);
      unsigned hi = f2bf(f2) | (f2bf(f3) << 16);
      int row = tp * 16 + c_s;
      int ua = row * 16 + ((slot ^ ((tp + c_s) & 7)) << 1);
      uint2 wv; wv.x = lo; wv.y = hi;
      *(uint2*)&xw_u[ua] = wv;
    }
  };

  // z lane constants: A-row m=col -> c_local = col>>2 (wave's quarter), t = col&3
  const int c_sz = w4 + (col >> 2);
  const int t_z  = col & 3;
  const int cs2  = w4 + g;       // C-row c for loss/zly (m = g*4+q -> c_local=g, t=q)

  f4v yacc[4][2];
#pragma unroll
  for (int i = 0; i < 4; ++i) {
    yacc[i][0] = (f4v){0.f, 0.f, 0.f, 0.f};
    yacc[i][1] = (f4v){0.f, 0.f, 0.f, 0.f};
  }
  float lossA[3] = {0.f, 0.f, 0.f};

  stage_xw(0);

  for (int p = 0; p < 4; ++p) {
#pragma unroll
    for (int s = 0; s < 3; ++s) {
      // prefetch y A-frags (global, L2-hot); used after BARRIER_B
      const unsigned short* a3p = w3p + (size_t)(s * 4 + p) * 1024 + col * 16 + g * 4;
      s4v a3_0 = *(const s4v*)(a3p);
      s4v a3_1 = *(const s4v*)(a3p + 256);
      s4v a3_2 = *(const s4v*)(a3p + 512);
      s4v a3_3 = *(const s4v*)(a3p + 768);

      const unsigned short* bs = wpack + (size_t)(b * 3 + s) * WL_SH + g * 128 + col * 8;

      __syncthreads();   // BARRIER_A: xw staged; prev y-reads of zly done

      // ---- z MFMA: 36 per wave (1 m-tile x 2 n-tiles x 18 K-steps) ----
      f4v za0 = {0.f, 0.f, 0.f, 0.f}, za1 = {0.f, 0.f, 0.f, 0.f};
#pragma unroll
      for (int k = 0; k < 9; ++k) {
        int tp = t_z + k;
        int rowb = (tp * 16 + c_sz) * 16;
        int key = (tp + c_sz) & 7;
#pragma unroll
        for (int vh = 0; vh < 2; ++vh) {
          int sw = ((vh * 4 + g) ^ key) << 1;
          uint2 ua = *(const uint2*)&xw_u[rowb + sw];
          s4v a = __builtin_bit_cast(s4v, ua);
          s8v bbv = *(const s8v*)(bs + (k * 2 + vh) * 512);
          s4v b0 = __builtin_shufflevector(bbv, bbv, 0, 1, 2, 3);
          s4v b1 = __builtin_shufflevector(bbv, bbv, 4, 5, 6, 7);
          za0 = __builtin_amdgcn_mfma_f32_16x16x16bf16_1k(a, b0, za0, 0, 0, 0);
          za1 = __builtin_amdgcn_mfma_f32_16x16x16bf16_1k(a, b1, za1, 0, 0, 0);
        }
      }

      // ---- loss + zly write ----
      const short* xw_s = (const short*)xw_u;
      float lp = 0.f;
#pragma unroll
      for (int q = 0; q < 4; ++q) {
        int tp = q + 8;
        int key = (tp + cs2) & 7;
        int rowb2 = (tp * 16 + cs2) * 32;
        {
          int i = col;
          float zv = za0[q];
          float xf = bf2f((unsigned short)xw_s[rowb2 + (((i >> 2) ^ key) << 2) + (i & 3)]);
          float d = zv - xf;
          lp = fmaf(d, d, lp);
          zly[(q * 32 + i) * 18 + cs2] = (short)f2bf(zv);
        }
        {
          int i = 16 + col;
          float zv = za1[q];
          zly[(q * 32 + i) * 18 + cs2] = (short)f2bf(zv);
          if (col < 9) {
            float xf = bf2f((unsigned short)xw_s[rowb2 + (((i >> 2) ^ key) << 2) + (i & 3)]);
            float d = zv - xf;
            lp = fmaf(d, d, lp);
          }
        }
      }
      lossA[s] += lp;

      __syncthreads();   // BARRIER_B: zly ready; xw reads of this phase done

      // ---- y MFMA: 8 per wave (4 mt x 2 nt), K=16 c ----
      const unsigned* zly_u = (const unsigned*)zly;
#pragma unroll
      for (int u = 0; u < 2; ++u) {
        int n = (wid * 2 + u) * 16 + col;
        int zo = n * 9 + g * 2;
        uint2 uz; uz.x = zly_u[zo]; uz.y = zly_u[zo + 1];
        s4v bz = __builtin_bit_cast(s4v, uz);
        yacc[0][u] = __builtin_amdgcn_mfma_f32_16x16x16bf16_1k(a3_0, bz, yacc[0][u], 0, 0, 0);
        yacc[1][u] = __builtin_amdgcn_mfma_f32_16x16x16bf16_1k(a3_1, bz, yacc[1][u], 0, 0, 0);
        yacc[2][u] = __builtin_amdgcn_mfma_f32_16x16x16bf16_1k(a3_2, bz, yacc[2][u], 0, 0, 0);
        yacc[3][u] = __builtin_amdgcn_mfma_f32_16x16x16bf16_1k(a3_3, bz, yacc[3][u], 0, 0, 0);
      }

      // stage next c-panel (xw fully consumed; zly untouched by staging)
      if (s == 2 && p < 3) stage_xw(p + 1);
    }
  }

  __syncthreads();

  // ---- loss reduce (xw region as scratch) ----
  {
    float* redf = (float*)xw_u;
#pragma unroll
    for (int s = 0; s < 3; ++s) {
      redf[tid] = lossA[s];
      __syncthreads();
      for (int st = 128; st > 0; st >>= 1) {
        if (tid < st) redf[tid] += redf[tid + st];
        __syncthreads();
      }
      if (tid == 0) lossP[(b * 64 + id) * 3 + s] = redf[0];
      __syncthreads();
    }
  }

  // ---- epilogue: y = relu(acc*inv + off + x) ----
#pragma unroll
  for (int u = 0; u < 2; ++u) {
    int n = (wid * 2 + u) * 16 + col;
    int t_out = n >> 5, i = n & 31;
    if (i < VDIM) {
      int gt = t0 + t_out;
#pragma unroll
      for (int mt = 0; mt < 4; ++mt) {
#pragma unroll
        for (int q = 0; q < 4; ++q) {
          int o = mt * 16 + g * 4 + q;
          size_t idx = ((size_t)(b * 64 + o) * TDIM + gt) * VDIM + i;
          float v = yacc[mt][u][q] * bnf[o] + bnf[64 + o] + x[idx];
          out[idx] = fmaxf(v, 0.f);
        }
      }
    }
  }
}

// ---------------- Kernel 4: finalize loss ----------------
__global__ __launch_bounds__(256) void kfin(const float* __restrict__ lossP,
                                            float* __restrict__ out_loss) {
  __shared__ float red[256];
  int tid = threadIdx.x;
  for (int s = 0; s < 3; ++s) {
    float a = 0.f;
    for (int i = tid; i < 2048; i += 256) a += lossP[i * 3 + s];
    red[tid] = a;
    __syncthreads();
    for (int st = 128; st > 0; st >>= 1) {
      if (tid < st) red[tid] += red[tid + st];
      __syncthreads();
    }
    if (tid == 0) out_loss[s] = red[0] * (1.f / 13107200.f);
    __syncthreads();
  }
}

extern "C" void kernel_launch(void* const* d_in, const int* in_sizes, int n_in,
                              void* d_out, int out_size, void* d_ws, size_t ws_size,
                              hipStream_t stream) {
  (void)in_sizes; (void)n_in; (void)out_size; (void)ws_size;
  const float* x     = (const float*)d_in[0];
  const float* A     = (const float*)d_in[1];
  const float* alpha = (const float*)d_in[2];
  const float* W1    = (const float*)d_in[3];
  const float* b1    = (const float*)d_in[4];
  const float* W2    = (const float*)d_in[5];
  const float* b2    = (const float*)d_in[6];
  const float* W3    = (const float*)d_in[7];
  const float* b3    = (const float*)d_in[8];
  const float* bng   = (const float*)d_in[9];
  const float* bnb   = (const float*)d_in[10];
  const float* bnm   = (const float*)d_in[11];
  const float* bnv   = (const float*)d_in[12];
  float* out = (float*)d_out;
  float* ws  = (float*)d_ws;
  float* out_loss  = out + 13107200;
  float* out_ridge = out + 13107203;
  float* lossP = ws + LOSSP_OFF;

  kmean<<<2048, 256, 0, stream>>>(x, ws);
  kadj<<<96, 256, 0, stream>>>(A, alpha, W1, b1, W2, b2, W3, ws, out_ridge);
  kmain<<<dim3(64, 32), 256, 0, stream>>>(x, b3, bng, bnb, bnm, bnv, ws, out, lossP);
  kfin<<<1, 256, 0, stream>>>(lossP, out_loss);
}

// Round 7
// 418.986 us; speedup vs baseline: 1.5318x; 1.3754x over previous
//
#include <hip/hip_runtime.h>
#include <hip/hip_bf16.h>

#define TDIM 256
#define VDIM 25
#define CDIM 64
#define BDIM 32
#define EPSV 1e-5f

// ws layout
#define XM_OFF     0            // 51200 floats
#define LOSSP_OFF  51200        // 6144 floats (2048 blocks * 3)
#define WPACK_BYTE 229376       // 96 packs * 9216 shorts (bf16 z B-frags)
#define WL_SH      9216         // shorts per (b,s): 18 kvh * 4 g * 16 col * 8
#define W3P_BYTE   (WPACK_BYTE + 96 * WL_SH * 2)  // 1998848; 3s*4096 shorts

typedef short s4v __attribute__((ext_vector_type(4)));
typedef short s8v __attribute__((ext_vector_type(8)));
typedef float f4v __attribute__((ext_vector_type(4)));

__device__ __forceinline__ unsigned f2bf(float f) {
  __hip_bfloat16 h = __float2bfloat16(f);
  return (unsigned)__builtin_bit_cast(unsigned short, h);
}
__device__ __forceinline__ float bf2f(unsigned short u) {
  unsigned v = ((unsigned)u) << 16;
  return __builtin_bit_cast(float, v);
}

// ---------------- Kernel 1: xm[b,c,v] = mean over T ----------------
__global__ __launch_bounds__(256) void kmean(const float* __restrict__ x,
                                             float* __restrict__ ws) {
  int bc = blockIdx.x;
  int tid = threadIdx.x;
  int vl = tid & 31, tr = tid >> 5;
  float acc = 0.f;
  if (vl < VDIM) {
    const float* p = x + (size_t)bc * TDIM * VDIM + vl;
    for (int t = tr; t < TDIM; t += 8) acc += p[(size_t)t * VDIM];
  }
  __shared__ float red[256];
  red[tid] = acc;
  __syncthreads();
  if (tr == 0 && vl < VDIM) {
    float s = 0.f;
    for (int r = 0; r < 8; ++r) s += red[r * 32 + vl];
    ws[XM_OFF + bc * VDIM + vl] = s * (1.f / 256.f);
  }
}

// ---------------- Kernel 2: dynamic weights -> packed bf16 fragments ----------------
__global__ __launch_bounds__(256) void kadj(const float* __restrict__ A,
                                            const float* __restrict__ alpha,
                                            const float* __restrict__ W1,
                                            const float* __restrict__ b1,
                                            const float* __restrict__ W2,
                                            const float* __restrict__ b2,
                                            const float* __restrict__ W3,
                                            float* __restrict__ ws,
                                            float* __restrict__ out_ridge) {
  int s = blockIdx.x >> 5, b = blockIdx.x & 31;
  int tid = threadIdx.x;
  __shared__ float xm[CDIM * VDIM];
  __shared__ float w1l[9 * CDIM], w2l[9 * CDIM];
  __shared__ float b1l[9], b2l[9];
  __shared__ float x1l[9 * VDIM], x2l[9 * VDIM];
  __shared__ float red[256];
  __shared__ float wsm[9 * VDIM * VDIM];   // w[k][v][i] f32

  for (int i = tid; i < CDIM * VDIM; i += 256) xm[i] = ws[XM_OFF + b * CDIM * VDIM + i];
  for (int i = tid; i < 9 * CDIM; i += 256) {
    w1l[i] = W1[s * 9 * CDIM + i];
    w2l[i] = W2[s * 9 * CDIM + i];
  }
  if (tid < 9) { b1l[tid] = b1[s * 9 + tid]; b2l[tid] = b2[s * 9 + tid]; }
  __syncthreads();

  if (tid < 9 * VDIM) {
    int ts = tid / VDIM, v = tid % VDIM;
    float a1 = 0.f, a2 = 0.f;
    for (int c = 0; c < CDIM; ++c) {
      float xv = xm[c * VDIM + v];
      a1 = fmaf(xv, w1l[ts * CDIM + c], a1);
      a2 = fmaf(xv, w2l[ts * CDIM + c], a2);
    }
    x1l[tid] = a1 + b1l[ts];
    x2l[tid] = a2 + b2l[ts];
  }
  __syncthreads();

  float al = alpha[0];
  float rid = 0.f;
  for (int idx = tid; idx < 9 * VDIM * VDIM; idx += 256) {
    int k = idx / (VDIM * VDIM);
    int r = (idx / VDIM) % VDIM;   // v
    int q = idx % VDIM;            // i
    float adj = tanhf(x1l[k * VDIM + r] - x2l[k * VDIM + q]);
    rid += adj * adj;
    wsm[idx] = fmaf(adj, al, A[(s * VDIM + r) * VDIM + q]);
  }
  red[tid] = rid;
  __syncthreads();   // wsm + red complete

  // pack z B-frags: [kvh 18][g 4][col 16][n2*j4]; k-element = (lane>>4)*4+j
  {
    unsigned short* wp = (unsigned short*)((char*)ws + WPACK_BYTE) + (size_t)(b * 3 + s) * WL_SH;
    for (int idx = tid; idx < WL_SH; idx += 256) {
      int kvh = idx >> 9;
      int rem = idx & 511;
      int gg = rem >> 7;
      int e = rem & 127;
      int colv = e >> 3;
      int q = e & 7;
      int n = q >> 2, jj = q & 3;
      int k = kvh >> 1, vh = kvh & 1;
      int v = vh * 16 + gg * 4 + jj;
      int i = n * 16 + colv;
      float val = (v < VDIM && i < VDIM) ? wsm[(k * VDIM + v) * VDIM + i] : 0.f;
      wp[idx] = (unsigned short)f2bf(val);
    }
  }

  for (int st = 128; st > 0; st >>= 1) {
    if (tid < st) red[tid] += red[tid + st];
    __syncthreads();
  }
  if (tid == 0) out_ridge[s * BDIM + b] = red[0];

  // pack W3 A-frags: [s][p][mt][col16][g4][j4]; A[m=o][k=c_local], c = p*16+g*4+j
  if (b == 0) {
    unsigned short* w3p = (unsigned short*)((char*)ws + W3P_BYTE) + s * 4096;
    for (int idx = tid; idx < 4096; idx += 256) {
      int pm = idx >> 8;          // p*4+mt
      int p = pm >> 2, mt = pm & 3;
      int e = idx & 255;
      int colv = e >> 4, gg = (e >> 2) & 3, jj = e & 3;
      int o = mt * 16 + colv, c = p * 16 + gg * 4 + jj;
      w3p[idx] = (unsigned short)f2bf(W3[(s * CDIM + o) * CDIM + c]);
    }
  }
}

// ---------------- Kernel 3: all-MFMA fused z -> (loss, y), t-tile = 4 ----------------
// xw: [tp12][c16] rows of 16 uints; v-granule gv at (gv ^ ((tp+c)&7))  (<=2-way reads)
// zly: [n=t*32+i 128][18 shorts]; z B-frags direct from global (L2-resident)
__global__ __launch_bounds__(256, 3) void kmain(const float* __restrict__ x,
                                                const float* __restrict__ b3,
                                                const float* __restrict__ bng,
                                                const float* __restrict__ bnb,
                                                const float* __restrict__ bnm,
                                                const float* __restrict__ bnv,
                                                const float* __restrict__ ws,
                                                float* __restrict__ out,
                                                float* __restrict__ lossP) {
  const int id   = blockIdx.x;                      // 0..63
  const int tile = ((id & 7) << 3) | (id >> 3);     // XCD-contiguous t-chunks
  const int b    = blockIdx.y;
  const int t0   = tile * 4;
  const int tid  = threadIdx.x;
  const int wid  = tid >> 6;
  const int lane = tid & 63;
  const int g    = lane >> 4;
  const int col  = lane & 15;
  const int w4   = wid * 4;

  __shared__ __align__(16) unsigned xw_u[3072];   // 12288 B: [tp12][c16] x 16u
  __shared__ __align__(16) short zly[2304];       // 4608 B: [n128][18]
  __shared__ float bnf[128];

  if (tid < 64) {
    float inv = bng[tid] / sqrtf(bnv[tid] + EPSV);
    bnf[tid] = inv;
    bnf[64 + tid] = (b3[tid] + b3[64 + tid] + b3[128 + tid] - bnm[tid]) * inv + bnb[tid];
  }

  const unsigned short* wpack = (const unsigned short*)((const char*)ws + WPACK_BYTE);
  const unsigned short* w3p   = (const unsigned short*)((const char*)ws + W3P_BYTE);

  auto stage_xw = [&](int p) {
    int c_s = tid >> 4, r = tid & 15, slot = r & 7, th = r >> 3;
    const float* xsrc = x + (size_t)(b * 64 + p * 16 + c_s) * TDIM * VDIM;
#pragma unroll
    for (int m = 0; m < 6; ++m) {
      int tp = m * 2 + th;
      int gt = t0 - 8 + tp;
      float f0 = 0.f, f1 = 0.f, f2 = 0.f, f3 = 0.f;
      if (gt >= 0 && slot < 7) {
        const float* rp = xsrc + (size_t)gt * VDIM + slot * 4;
        if (slot < 6) { float4 q4 = *(const float4*)rp; f0 = q4.x; f1 = q4.y; f2 = q4.z; f3 = q4.w; }
        else f0 = rp[0];   // slot 6: only v=24 valid
      }
      unsigned lo = f2bf(f0) | (f2bf(f1) << 16);
      unsigned hi = f2bf(f2) | (f2bf(f3) << 16);
      int row = tp * 16 + c_s;
      int ua = row * 16 + ((slot ^ ((tp + c_s) & 7)) << 1);
      uint2 wv; wv.x = lo; wv.y = hi;
      *(uint2*)&xw_u[ua] = wv;
    }
  };

  // z lane constants: A-row m=col -> c_local = col>>2 (wave's quarter), t = col&3
  const int c_sz = w4 + (col >> 2);
  const int t_z  = col & 3;
  const int cs2  = w4 + g;       // C-row c for loss/zly (m = g*4+q -> c_local=g, t=q)

  f4v yacc[4][2];
#pragma unroll
  for (int i = 0; i < 4; ++i) {
    yacc[i][0] = (f4v){0.f, 0.f, 0.f, 0.f};
    yacc[i][1] = (f4v){0.f, 0.f, 0.f, 0.f};
  }
  float lossA[3] = {0.f, 0.f, 0.f};

  stage_xw(0);

  for (int p = 0; p < 4; ++p) {
#pragma unroll
    for (int s = 0; s < 3; ++s) {
      // prefetch y A-frags (global, L2-hot); used after BARRIER_B
      const unsigned short* a3p = w3p + (size_t)(s * 4 + p) * 1024 + col * 16 + g * 4;
      s4v a3_0 = *(const s4v*)(a3p);
      s4v a3_1 = *(const s4v*)(a3p + 256);
      s4v a3_2 = *(const s4v*)(a3p + 512);
      s4v a3_3 = *(const s4v*)(a3p + 768);

      const unsigned short* bs = wpack + (size_t)(b * 3 + s) * WL_SH + g * 128 + col * 8;

      __syncthreads();   // BARRIER_A: xw staged; prev y-reads of zly done

      // ---- z MFMA: 36 per wave (1 m-tile x 2 n-tiles x 18 K-steps) ----
      f4v za0 = {0.f, 0.f, 0.f, 0.f}, za1 = {0.f, 0.f, 0.f, 0.f};
#pragma unroll
      for (int k = 0; k < 9; ++k) {
        int tp = t_z + k;
        int rowb = (tp * 16 + c_sz) * 16;
        int key = (tp + c_sz) & 7;
#pragma unroll
        for (int vh = 0; vh < 2; ++vh) {
          int sw = ((vh * 4 + g) ^ key) << 1;
          uint2 ua = *(const uint2*)&xw_u[rowb + sw];
          s4v a = __builtin_bit_cast(s4v, ua);
          s8v bbv = *(const s8v*)(bs + (k * 2 + vh) * 512);
          s4v b0 = __builtin_shufflevector(bbv, bbv, 0, 1, 2, 3);
          s4v b1 = __builtin_shufflevector(bbv, bbv, 4, 5, 6, 7);
          za0 = __builtin_amdgcn_mfma_f32_16x16x16bf16_1k(a, b0, za0, 0, 0, 0);
          za1 = __builtin_amdgcn_mfma_f32_16x16x16bf16_1k(a, b1, za1, 0, 0, 0);
        }
      }

      // ---- loss + zly write ----
      const short* xw_s = (const short*)xw_u;
      float lp = 0.f;
#pragma unroll
      for (int q = 0; q < 4; ++q) {
        int tp = q + 8;
        int key = (tp + cs2) & 7;
        int rowb2 = (tp * 16 + cs2) * 32;
        {
          int i = col;
          float zv = za0[q];
          float xf = bf2f((unsigned short)xw_s[rowb2 + (((i >> 2) ^ key) << 2) + (i & 3)]);
          float d = zv - xf;
          lp = fmaf(d, d, lp);
          zly[(q * 32 + i) * 18 + cs2] = (short)f2bf(zv);
        }
        {
          int i = 16 + col;
          float zv = za1[q];
          zly[(q * 32 + i) * 18 + cs2] = (short)f2bf(zv);
          if (col < 9) {
            float xf = bf2f((unsigned short)xw_s[rowb2 + (((i >> 2) ^ key) << 2) + (i & 3)]);
            float d = zv - xf;
            lp = fmaf(d, d, lp);
          }
        }
      }
      lossA[s] += lp;

      __syncthreads();   // BARRIER_B: zly ready; xw reads of this phase done

      // ---- y MFMA: 8 per wave (4 mt x 2 nt), K=16 c ----
      const unsigned* zly_u = (const unsigned*)zly;
#pragma unroll
      for (int u = 0; u < 2; ++u) {
        int n = (wid * 2 + u) * 16 + col;
        int zo = n * 9 + g * 2;
        uint2 uz; uz.x = zly_u[zo]; uz.y = zly_u[zo + 1];
        s4v bz = __builtin_bit_cast(s4v, uz);
        yacc[0][u] = __builtin_amdgcn_mfma_f32_16x16x16bf16_1k(a3_0, bz, yacc[0][u], 0, 0, 0);
        yacc[1][u] = __builtin_amdgcn_mfma_f32_16x16x16bf16_1k(a3_1, bz, yacc[1][u], 0, 0, 0);
        yacc[2][u] = __builtin_amdgcn_mfma_f32_16x16x16bf16_1k(a3_2, bz, yacc[2][u], 0, 0, 0);
        yacc[3][u] = __builtin_amdgcn_mfma_f32_16x16x16bf16_1k(a3_3, bz, yacc[3][u], 0, 0, 0);
      }

      // stage next c-panel (xw fully consumed; zly untouched by staging)
      if (s == 2 && p < 3) stage_xw(p + 1);
    }
  }

  __syncthreads();

  // ---- loss reduce (xw region as scratch) ----
  {
    float* redf = (float*)xw_u;
#pragma unroll
    for (int s = 0; s < 3; ++s) {
      redf[tid] = lossA[s];
      __syncthreads();
      for (int st = 128; st > 0; st >>= 1) {
        if (tid < st) redf[tid] += redf[tid + st];
        __syncthreads();
      }
      if (tid == 0) lossP[(b * 64 + id) * 3 + s] = redf[0];
      __syncthreads();
    }
  }

  // ---- epilogue: y = relu(acc*inv + off + x) ----
#pragma unroll
  for (int u = 0; u < 2; ++u) {
    int n = (wid * 2 + u) * 16 + col;
    int t_out = n >> 5, i = n & 31;
    if (i < VDIM) {
      int gt = t0 + t_out;
#pragma unroll
      for (int mt = 0; mt < 4; ++mt) {
#pragma unroll
        for (int q = 0; q < 4; ++q) {
          int o = mt * 16 + g * 4 + q;
          size_t idx = ((size_t)(b * 64 + o) * TDIM + gt) * VDIM + i;
          float v = yacc[mt][u][q] * bnf[o] + bnf[64 + o] + x[idx];
          out[idx] = fmaxf(v, 0.f);
        }
      }
    }
  }
}

// ---------------- Kernel 4: finalize loss ----------------
__global__ __launch_bounds__(256) void kfin(const float* __restrict__ lossP,
                                            float* __restrict__ out_loss) {
  __shared__ float red[256];
  int tid = threadIdx.x;
  for (int s = 0; s < 3; ++s) {
    float a = 0.f;
    for (int i = tid; i < 2048; i += 256) a += lossP[i * 3 + s];
    red[tid] = a;
    __syncthreads();
    for (int st = 128; st > 0; st >>= 1) {
      if (tid < st) red[tid] += red[tid + st];
      __syncthreads();
    }
    if (tid == 0) out_loss[s] = red[0] * (1.f / 13107200.f);
    __syncthreads();
  }
}

extern "C" void kernel_launch(void* const* d_in, const int* in_sizes, int n_in,
                              void* d_out, int out_size, void* d_ws, size_t ws_size,
                              hipStream_t stream) {
  (void)in_sizes; (void)n_in; (void)out_size; (void)ws_size;
  const float* x     = (const float*)d_in[0];
  const float* A     = (const float*)d_in[1];
  const float* alpha = (const float*)d_in[2];
  const float* W1    = (const float*)d_in[3];
  const float* b1    = (const float*)d_in[4];
  const float* W2    = (const float*)d_in[5];
  const float* b2    = (const float*)d_in[6];
  const float* W3    = (const float*)d_in[7];
  const float* b3    = (const float*)d_in[8];
  const float* bng   = (const float*)d_in[9];
  const float* bnb   = (const float*)d_in[10];
  const float* bnm   = (const float*)d_in[11];
  const float* bnv   = (const float*)d_in[12];
  float* out = (float*)d_out;
  float* ws  = (float*)d_ws;
  float* out_loss  = out + 13107200;
  float* out_ridge = out + 13107203;
  float* lossP = ws + LOSSP_OFF;

  kmean<<<2048, 256, 0, stream>>>(x, ws);
  kadj<<<96, 256, 0, stream>>>(A, alpha, W1, b1, W2, b2, W3, ws, out_ridge);
  kmain<<<dim3(64, 32), 256, 0, stream>>>(x, b3, bng, bnb, bnm, bnv, ws, out, lossP);
  kfin<<<1, 256, 0, stream>>>(lossP, out_loss);
}

// Round 8
// 149.966 us; speedup vs baseline: 4.2795x; 2.7939x over previous
//
#include <hip/hip_runtime.h>
#include <hip/hip_bf16.h>

#define TDIM 256
#define VDIM 25
#define CDIM 64
#define BDIM 32
#define EPSV 1e-5f

// ws layout
#define XM_OFF     0            // 51200 floats
#define LOSSP_OFF  51200        // 6144 floats (2048 blocks * 3)
#define WPACK_BYTE 229376       // 96 packs * 9216 shorts (bf16 z B-frags)
#define WL_SH      9216         // shorts per (b,s): 18 kvh * 4 g * 16 col * 8
#define W3P_BYTE   (WPACK_BYTE + 96 * WL_SH * 2)  // 1998848; 3s*4096 shorts

typedef short s4v __attribute__((ext_vector_type(4)));
typedef short s8v __attribute__((ext_vector_type(8)));
typedef float f4v __attribute__((ext_vector_type(4)));

__device__ __forceinline__ unsigned f2bf(float f) {
  __hip_bfloat16 h = __float2bfloat16(f);
  return (unsigned)__builtin_bit_cast(unsigned short, h);
}
__device__ __forceinline__ float bf2f(unsigned short u) {
  unsigned v = ((unsigned)u) << 16;
  return __builtin_bit_cast(float, v);
}

// ---------------- Kernel 1: xm[b,c,v] = mean over T ----------------
__global__ __launch_bounds__(256) void kmean(const float* __restrict__ x,
                                             float* __restrict__ ws) {
  int bc = blockIdx.x;
  int tid = threadIdx.x;
  int vl = tid & 31, tr = tid >> 5;
  float acc = 0.f;
  if (vl < VDIM) {
    const float* p = x + (size_t)bc * TDIM * VDIM + vl;
    for (int t = tr; t < TDIM; t += 8) acc += p[(size_t)t * VDIM];
  }
  __shared__ float red[256];
  red[tid] = acc;
  __syncthreads();
  if (tr == 0 && vl < VDIM) {
    float s = 0.f;
    for (int r = 0; r < 8; ++r) s += red[r * 32 + vl];
    ws[XM_OFF + bc * VDIM + vl] = s * (1.f / 256.f);
  }
}

// ---------------- Kernel 2: dynamic weights -> packed bf16 fragments ----------------
__global__ __launch_bounds__(256) void kadj(const float* __restrict__ A,
                                            const float* __restrict__ alpha,
                                            const float* __restrict__ W1,
                                            const float* __restrict__ b1,
                                            const float* __restrict__ W2,
                                            const float* __restrict__ b2,
                                            const float* __restrict__ W3,
                                            float* __restrict__ ws,
                                            float* __restrict__ out_ridge) {
  int s = blockIdx.x >> 5, b = blockIdx.x & 31;
  int tid = threadIdx.x;
  __shared__ float xm[CDIM * VDIM];
  __shared__ float w1l[9 * CDIM], w2l[9 * CDIM];
  __shared__ float b1l[9], b2l[9];
  __shared__ float x1l[9 * VDIM], x2l[9 * VDIM];
  __shared__ float red[256];
  __shared__ float wsm[9 * VDIM * VDIM];   // w[k][v][i] f32

  for (int i = tid; i < CDIM * VDIM; i += 256) xm[i] = ws[XM_OFF + b * CDIM * VDIM + i];
  for (int i = tid; i < 9 * CDIM; i += 256) {
    w1l[i] = W1[s * 9 * CDIM + i];
    w2l[i] = W2[s * 9 * CDIM + i];
  }
  if (tid < 9) { b1l[tid] = b1[s * 9 + tid]; b2l[tid] = b2[s * 9 + tid]; }
  __syncthreads();

  if (tid < 9 * VDIM) {
    int ts = tid / VDIM, v = tid % VDIM;
    float a1 = 0.f, a2 = 0.f;
    for (int c = 0; c < CDIM; ++c) {
      float xv = xm[c * VDIM + v];
      a1 = fmaf(xv, w1l[ts * CDIM + c], a1);
      a2 = fmaf(xv, w2l[ts * CDIM + c], a2);
    }
    x1l[tid] = a1 + b1l[ts];
    x2l[tid] = a2 + b2l[ts];
  }
  __syncthreads();

  float al = alpha[0];
  float rid = 0.f;
  for (int idx = tid; idx < 9 * VDIM * VDIM; idx += 256) {
    int k = idx / (VDIM * VDIM);
    int r = (idx / VDIM) % VDIM;   // v
    int q = idx % VDIM;            // i
    float adj = tanhf(x1l[k * VDIM + r] - x2l[k * VDIM + q]);
    rid += adj * adj;
    wsm[idx] = fmaf(adj, al, A[(s * VDIM + r) * VDIM + q]);
  }
  red[tid] = rid;
  __syncthreads();   // wsm + red complete

  // pack z B-frags: [kvh 18][g 4][col 16][n2*j4]; k-element = (lane>>4)*4+j
  {
    unsigned short* wp = (unsigned short*)((char*)ws + WPACK_BYTE) + (size_t)(b * 3 + s) * WL_SH;
    for (int idx = tid; idx < WL_SH; idx += 256) {
      int kvh = idx >> 9;
      int rem = idx & 511;
      int gg = rem >> 7;
      int e = rem & 127;
      int colv = e >> 3;
      int q = e & 7;
      int n = q >> 2, jj = q & 3;
      int k = kvh >> 1, vh = kvh & 1;
      int v = vh * 16 + gg * 4 + jj;
      int i = n * 16 + colv;
      float val = (v < VDIM && i < VDIM) ? wsm[(k * VDIM + v) * VDIM + i] : 0.f;
      wp[idx] = (unsigned short)f2bf(val);
    }
  }

  for (int st = 128; st > 0; st >>= 1) {
    if (tid < st) red[tid] += red[tid + st];
    __syncthreads();
  }
  if (tid == 0) out_ridge[s * BDIM + b] = red[0];

  // pack W3 A-frags: [s][p][mt][col16][g4][j4]; A[m=o][k=c_local], c = p*16+g*4+j
  if (b == 0) {
    unsigned short* w3p = (unsigned short*)((char*)ws + W3P_BYTE) + s * 4096;
    for (int idx = tid; idx < 4096; idx += 256) {
      int pm = idx >> 8;          // p*4+mt
      int p = pm >> 2, mt = pm & 3;
      int e = idx & 255;
      int colv = e >> 4, gg = (e >> 2) & 3, jj = e & 3;
      int o = mt * 16 + colv, c = p * 16 + gg * 4 + jj;
      w3p[idx] = (unsigned short)f2bf(W3[(s * CDIM + o) * CDIM + c]);
    }
  }
}

// ---------------- Kernel 3: all-MFMA fused z -> (loss, y), t-tile = 4 ----------------
// wl: z B-frags for current s, staged via global_load_lds (linear, no VGPR roundtrip)
// xw: [tp12][c16] rows of 16 uints; v-granule gv at (gv ^ ((tp+c)&7))
// zly: [n=t*32+i 128][18 shorts]
__global__ __launch_bounds__(256, 3) void kmain(const float* __restrict__ x,
                                                const float* __restrict__ b3,
                                                const float* __restrict__ bng,
                                                const float* __restrict__ bnb,
                                                const float* __restrict__ bnm,
                                                const float* __restrict__ bnv,
                                                const float* __restrict__ ws,
                                                float* __restrict__ out,
                                                float* __restrict__ lossP) {
  const int id   = blockIdx.x;                      // 0..63
  const int tile = ((id & 7) << 3) | (id >> 3);     // XCD-contiguous t-chunks
  const int b    = blockIdx.y;
  const int t0   = tile * 4;
  const int tid  = threadIdx.x;
  const int wid  = tid >> 6;
  const int lane = tid & 63;
  const int g    = lane >> 4;
  const int col  = lane & 15;
  const int w4   = wid * 4;

  __shared__ __align__(16) short wl[WL_SH];       // 18432 B
  __shared__ __align__(16) unsigned xw_u[3072];   // 12288 B: [tp12][c16] x 16u
  __shared__ __align__(16) short zly[2304];       // 4608 B: [n128][18]
  __shared__ float bnf[128];

  if (tid < 64) {
    float inv = bng[tid] / sqrtf(bnv[tid] + EPSV);
    bnf[tid] = inv;
    bnf[64 + tid] = (b3[tid] + b3[64 + tid] + b3[128 + tid] - bnm[tid]) * inv + bnb[tid];
  }

  const unsigned short* wpack = (const unsigned short*)((const char*)ws + WPACK_BYTE);
  const unsigned short* w3p   = (const unsigned short*)((const char*)ws + W3P_BYTE);

  // async global->LDS stage of one s-pack (18432 B, 18 wave-chunks of 1024 B)
  auto stage_wl = [&](int s2) {
    const char* src = (const char*)(wpack + (size_t)(b * 3 + s2) * WL_SH);
#pragma unroll
    for (int j = 0; j < 5; ++j) {
      int off = j * 4096 + wid * 1024;
      if (off < WL_SH * 2) {
        __builtin_amdgcn_global_load_lds(
            (const __attribute__((address_space(1))) unsigned*)(src + off + lane * 16),
            (__attribute__((address_space(3))) unsigned*)((char*)wl + off + lane * 16),
            16, 0, 0);
      }
    }
  };

  auto stage_xw = [&](int p) {
    int c_s = tid >> 4, r = tid & 15, slot = r & 7, th = r >> 3;
    const float* xsrc = x + (size_t)(b * 64 + p * 16 + c_s) * TDIM * VDIM;
#pragma unroll
    for (int m = 0; m < 6; ++m) {
      int tp = m * 2 + th;
      int gt = t0 - 8 + tp;
      float f0 = 0.f, f1 = 0.f, f2 = 0.f, f3 = 0.f;
      if (gt >= 0 && slot < 7) {
        const float* rp = xsrc + (size_t)gt * VDIM + slot * 4;
        if (slot < 6) { float4 q4 = *(const float4*)rp; f0 = q4.x; f1 = q4.y; f2 = q4.z; f3 = q4.w; }
        else f0 = rp[0];   // slot 6: only v=24 valid
      }
      unsigned lo = f2bf(f0) | (f2bf(f1) << 16);
      unsigned hi = f2bf(f2) | (f2bf(f3) << 16);
      int row = tp * 16 + c_s;
      int ua = row * 16 + ((slot ^ ((tp + c_s) & 7)) << 1);
      uint2 wv; wv.x = lo; wv.y = hi;
      *(uint2*)&xw_u[ua] = wv;
    }
  };

  // z lane constants: A-row m=col -> c_local = col>>2 (wave's quarter), t = col&3
  const int c_sz = w4 + (col >> 2);
  const int t_z  = col & 3;
  const int cs2  = w4 + g;       // C-row c for loss/zly (m = g*4+q -> c_local=g, t=q)
  const short* bs = wl + g * 128 + col * 8;

  f4v yacc[4][2];
#pragma unroll
  for (int i = 0; i < 4; ++i) {
    yacc[i][0] = (f4v){0.f, 0.f, 0.f, 0.f};
    yacc[i][1] = (f4v){0.f, 0.f, 0.f, 0.f};
  }
  float lossA[3] = {0.f, 0.f, 0.f};

  stage_xw(0);
  stage_wl(0);

  for (int p = 0; p < 4; ++p) {
#pragma unroll
    for (int s = 0; s < 3; ++s) {
      // prefetch y A-frags (global, L2-hot); used after BARRIER_B
      const unsigned short* a3p = w3p + (size_t)(s * 4 + p) * 1024 + col * 16 + g * 4;
      s4v a3_0 = *(const s4v*)(a3p);
      s4v a3_1 = *(const s4v*)(a3p + 256);
      s4v a3_2 = *(const s4v*)(a3p + 512);
      s4v a3_3 = *(const s4v*)(a3p + 768);

      __syncthreads();   // BARRIER_A: drains gload_lds (wl) + xw stores

      // ---- z MFMA: 36 per wave (1 m-tile x 2 n-tiles x 18 K-steps) ----
      f4v za0 = {0.f, 0.f, 0.f, 0.f}, za1 = {0.f, 0.f, 0.f, 0.f};
#pragma unroll
      for (int k = 0; k < 9; ++k) {
        int tp = t_z + k;
        int rowb = (tp * 16 + c_sz) * 16;
        int key = (tp + c_sz) & 7;
#pragma unroll
        for (int vh = 0; vh < 2; ++vh) {
          int sw = ((vh * 4 + g) ^ key) << 1;
          uint2 ua = *(const uint2*)&xw_u[rowb + sw];
          s4v a = __builtin_bit_cast(s4v, ua);
          s8v bbv = *(const s8v*)(bs + (k * 2 + vh) * 512);
          s4v b0 = __builtin_shufflevector(bbv, bbv, 0, 1, 2, 3);
          s4v b1 = __builtin_shufflevector(bbv, bbv, 4, 5, 6, 7);
          za0 = __builtin_amdgcn_mfma_f32_16x16x16bf16_1k(a, b0, za0, 0, 0, 0);
          za1 = __builtin_amdgcn_mfma_f32_16x16x16bf16_1k(a, b1, za1, 0, 0, 0);
        }
      }

      // ---- loss + zly write ----
      const short* xw_s = (const short*)xw_u;
      float lp = 0.f;
#pragma unroll
      for (int q = 0; q < 4; ++q) {
        int tp = q + 8;
        int key = (tp + cs2) & 7;
        int rowb2 = (tp * 16 + cs2) * 32;
        {
          int i = col;
          float zv = za0[q];
          float xf = bf2f((unsigned short)xw_s[rowb2 + (((i >> 2) ^ key) << 2) + (i & 3)]);
          float d = zv - xf;
          lp = fmaf(d, d, lp);
          zly[(q * 32 + i) * 18 + cs2] = (short)f2bf(zv);
        }
        {
          int i = 16 + col;
          float zv = za1[q];
          zly[(q * 32 + i) * 18 + cs2] = (short)f2bf(zv);
          if (col < 9) {
            float xf = bf2f((unsigned short)xw_s[rowb2 + (((i >> 2) ^ key) << 2) + (i & 3)]);
            float d = zv - xf;
            lp = fmaf(d, d, lp);
          }
        }
      }
      lossA[s] += lp;

      __syncthreads();   // BARRIER_B: zly ready; wl/xw reads of this phase done

      // ---- y MFMA: 8 per wave (4 mt x 2 nt), K=16 c ----
      const unsigned* zly_u = (const unsigned*)zly;
#pragma unroll
      for (int u = 0; u < 2; ++u) {
        int n = (wid * 2 + u) * 16 + col;
        int zo = n * 9 + g * 2;
        uint2 uz; uz.x = zly_u[zo]; uz.y = zly_u[zo + 1];
        s4v bz = __builtin_bit_cast(s4v, uz);
        yacc[0][u] = __builtin_amdgcn_mfma_f32_16x16x16bf16_1k(a3_0, bz, yacc[0][u], 0, 0, 0);
        yacc[1][u] = __builtin_amdgcn_mfma_f32_16x16x16bf16_1k(a3_1, bz, yacc[1][u], 0, 0, 0);
        yacc[2][u] = __builtin_amdgcn_mfma_f32_16x16x16bf16_1k(a3_2, bz, yacc[2][u], 0, 0, 0);
        yacc[3][u] = __builtin_amdgcn_mfma_f32_16x16x16bf16_1k(a3_3, bz, yacc[3][u], 0, 0, 0);
      }

      // stage next buffers in the y-phase shadow (all wl/xw reads complete)
      if (s < 2) {
        stage_wl(s + 1);
      } else if (p < 3) {
        stage_wl(0);
        stage_xw(p + 1);
      }
    }
  }

  __syncthreads();

  // ---- loss reduce (xw region as scratch) ----
  {
    float* redf = (float*)xw_u;
#pragma unroll
    for (int s = 0; s < 3; ++s) {
      redf[tid] = lossA[s];
      __syncthreads();
      for (int st = 128; st > 0; st >>= 1) {
        if (tid < st) redf[tid] += redf[tid + st];
        __syncthreads();
      }
      if (tid == 0) lossP[(b * 64 + id) * 3 + s] = redf[0];
      __syncthreads();
    }
  }

  // ---- epilogue: y = relu(acc*inv + off + x) ----
#pragma unroll
  for (int u = 0; u < 2; ++u) {
    int n = (wid * 2 + u) * 16 + col;
    int t_out = n >> 5, i = n & 31;
    if (i < VDIM) {
      int gt = t0 + t_out;
#pragma unroll
      for (int mt = 0; mt < 4; ++mt) {
#pragma unroll
        for (int q = 0; q < 4; ++q) {
          int o = mt * 16 + g * 4 + q;
          size_t idx = ((size_t)(b * 64 + o) * TDIM + gt) * VDIM + i;
          float v = yacc[mt][u][q] * bnf[o] + bnf[64 + o] + x[idx];
          out[idx] = fmaxf(v, 0.f);
        }
      }
    }
  }
}

// ---------------- Kernel 4: finalize loss ----------------
__global__ __launch_bounds__(256) void kfin(const float* __restrict__ lossP,
                                            float* __restrict__ out_loss) {
  __shared__ float red[256];
  int tid = threadIdx.x;
  for (int s = 0; s < 3; ++s) {
    float a = 0.f;
    for (int i = tid; i < 2048; i += 256) a += lossP[i * 3 + s];
    red[tid] = a;
    __syncthreads();
    for (int st = 128; st > 0; st >>= 1) {
      if (tid < st) red[tid] += red[tid + st];
      __syncthreads();
    }
    if (tid == 0) out_loss[s] = red[0] * (1.f / 13107200.f);
    __syncthreads();
  }
}

extern "C" void kernel_launch(void* const* d_in, const int* in_sizes, int n_in,
                              void* d_out, int out_size, void* d_ws, size_t ws_size,
                              hipStream_t stream) {
  (void)in_sizes; (void)n_in; (void)out_size; (void)ws_size;
  const float* x     = (const float*)d_in[0];
  const float* A     = (const float*)d_in[1];
  const float* alpha = (const float*)d_in[2];
  const float* W1    = (const float*)d_in[3];
  const float* b1    = (const float*)d_in[4];
  const float* W2    = (const float*)d_in[5];
  const float* b2    = (const float*)d_in[6];
  const float* W3    = (const float*)d_in[7];
  const float* b3    = (const float*)d_in[8];
  const float* bng   = (const float*)d_in[9];
  const float* bnb   = (const float*)d_in[10];
  const float* bnm   = (const float*)d_in[11];
  const float* bnv   = (const float*)d_in[12];
  float* out = (float*)d_out;
  float* ws  = (float*)d_ws;
  float* out_loss  = out + 13107200;
  float* out_ridge = out + 13107203;
  float* lossP = ws + LOSSP_OFF;

  kmean<<<2048, 256, 0, stream>>>(x, ws);
  kadj<<<96, 256, 0, stream>>>(A, alpha, W1, b1, W2, b2, W3, ws, out_ridge);
  kmain<<<dim3(64, 32), 256, 0, stream>>>(x, b3, bng, bnb, bnm, bnv, ws, out, lossP);
  kfin<<<1, 256, 0, stream>>>(lossP, out_loss);
}

// Round 10
// 148.325 us; speedup vs baseline: 4.3269x; 1.0111x over previous
//
#include <hip/hip_runtime.h>
#include <hip/hip_bf16.h>

#define TDIM 256
#define VDIM 25
#define CDIM 64
#define BDIM 32
#define EPSV 1e-5f

// ws layout
#define XM_OFF     0            // 51200 floats
#define LOSSP_OFF  51200        // 3072 floats (1024 blocks * 3)
#define WPACK_BYTE 229376       // 96 packs * 9216 shorts (bf16 z B-frags, 32x32x16)
#define WL_SH      9216         // shorts per (b,s): 18 kk * (2 hf * 32 n * 8 j)
#define W3P_BYTE   (WPACK_BYTE + 96 * WL_SH * 2)  // 3s*4096 shorts (y A-frags, 16x16x16)

typedef short s4v __attribute__((ext_vector_type(4)));
typedef short s8v __attribute__((ext_vector_type(8)));
typedef float f4v __attribute__((ext_vector_type(4)));
typedef float f16v __attribute__((ext_vector_type(16)));

__device__ __forceinline__ unsigned f2bf(float f) {
  __hip_bfloat16 h = __float2bfloat16(f);
  return (unsigned)__builtin_bit_cast(unsigned short, h);
}
__device__ __forceinline__ float bf2f(unsigned short u) {
  unsigned v = ((unsigned)u) << 16;
  return __builtin_bit_cast(float, v);
}

// ---------------- Kernel 1: xm[b,c,v] = mean over T ----------------
__global__ __launch_bounds__(256) void kmean(const float* __restrict__ x,
                                             float* __restrict__ ws) {
  int bc = blockIdx.x;
  int tid = threadIdx.x;
  int vl = tid & 31, tr = tid >> 5;
  float acc = 0.f;
  if (vl < VDIM) {
    const float* p = x + (size_t)bc * TDIM * VDIM + vl;
    for (int t = tr; t < TDIM; t += 8) acc += p[(size_t)t * VDIM];
  }
  __shared__ float red[256];
  red[tid] = acc;
  __syncthreads();
  if (tr == 0 && vl < VDIM) {
    float s = 0.f;
    for (int r = 0; r < 8; ++r) s += red[r * 32 + vl];
    ws[XM_OFF + bc * VDIM + vl] = s * (1.f / 256.f);
  }
}

// ---------------- Kernel 2: dynamic weights -> packed bf16 fragments ----------------
__global__ __launch_bounds__(256) void kadj(const float* __restrict__ A,
                                            const float* __restrict__ alpha,
                                            const float* __restrict__ W1,
                                            const float* __restrict__ b1,
                                            const float* __restrict__ W2,
                                            const float* __restrict__ b2,
                                            const float* __restrict__ W3,
                                            float* __restrict__ ws,
                                            float* __restrict__ out_ridge) {
  int s = blockIdx.x >> 5, b = blockIdx.x & 31;
  int tid = threadIdx.x;
  __shared__ float xm[CDIM * VDIM];
  __shared__ float w1l[9 * CDIM], w2l[9 * CDIM];
  __shared__ float b1l[9], b2l[9];
  __shared__ float x1l[9 * VDIM], x2l[9 * VDIM];
  __shared__ float red[256];
  __shared__ float wsm[9 * VDIM * VDIM];   // w[k][v][i] f32

  for (int i = tid; i < CDIM * VDIM; i += 256) xm[i] = ws[XM_OFF + b * CDIM * VDIM + i];
  for (int i = tid; i < 9 * CDIM; i += 256) {
    w1l[i] = W1[s * 9 * CDIM + i];
    w2l[i] = W2[s * 9 * CDIM + i];
  }
  if (tid < 9) { b1l[tid] = b1[s * 9 + tid]; b2l[tid] = b2[s * 9 + tid]; }
  __syncthreads();

  if (tid < 9 * VDIM) {
    int ts = tid / VDIM, v = tid % VDIM;
    float a1 = 0.f, a2 = 0.f;
    for (int c = 0; c < CDIM; ++c) {
      float xv = xm[c * VDIM + v];
      a1 = fmaf(xv, w1l[ts * CDIM + c], a1);
      a2 = fmaf(xv, w2l[ts * CDIM + c], a2);
    }
    x1l[tid] = a1 + b1l[ts];
    x2l[tid] = a2 + b2l[ts];
  }
  __syncthreads();

  float al = alpha[0];
  float rid = 0.f;
  for (int idx = tid; idx < 9 * VDIM * VDIM; idx += 256) {
    int k = idx / (VDIM * VDIM);
    int r = (idx / VDIM) % VDIM;   // v
    int q = idx % VDIM;            // i
    float adj = tanhf(x1l[k * VDIM + r] - x2l[k * VDIM + q]);
    rid += adj * adj;
    wsm[idx] = fmaf(adj, al, A[(s * VDIM + r) * VDIM + q]);
  }
  red[tid] = rid;
  __syncthreads();   // wsm + red complete

  // pack z B-frags for 32x32x16: [kk 18][hf 2][n 32][j 8]
  // so that lane l (n=l&31, hf=l>>5) reads its 8 shorts at wl + l*8:
  //   l*8 + j  ==  hf*256 + n*8 + j   (hf = l>>5, n = l&31)  -- FIXED vs r9
  {
    unsigned short* wp = (unsigned short*)((char*)ws + WPACK_BYTE) + (size_t)(b * 3 + s) * WL_SH;
    for (int idx = tid; idx < WL_SH; idx += 256) {
      int kk = idx >> 9;           // 0..17
      int rem = idx & 511;
      int hf = rem >> 8;           // 0..1
      int n = (rem >> 3) & 31;     // i
      int j = rem & 7;
      int k = kk >> 1, vh = kk & 1;
      int v = vh * 16 + hf * 8 + j;
      float val = (v < VDIM && n < VDIM) ? wsm[(k * VDIM + v) * VDIM + n] : 0.f;
      wp[idx] = (unsigned short)f2bf(val);
    }
  }

  for (int st = 128; st > 0; st >>= 1) {
    if (tid < st) red[tid] += red[tid + st];
    __syncthreads();
  }
  if (tid == 0) out_ridge[s * BDIM + b] = red[0];

  // pack W3 A-frags (16x16x16): [s][p][mt][col16][g4][j4]
  if (b == 0) {
    unsigned short* w3p = (unsigned short*)((char*)ws + W3P_BYTE) + s * 4096;
    for (int idx = tid; idx < 4096; idx += 256) {
      int pm = idx >> 8;          // p*4+mt
      int p = pm >> 2, mt = pm & 3;
      int e = idx & 255;
      int colv = e >> 4, gg = (e >> 2) & 3, jj = e & 3;
      int o = mt * 16 + colv, c = p * 16 + gg * 4 + jj;
      w3p[idx] = (unsigned short)f2bf(W3[(s * CDIM + o) * CDIM + c]);
    }
  }
}

// ---------------- Kernel 3: fused z(32x32 MFMA) -> (loss, y(16x16)), t-tile = 8 ----------------
// xw: [c16][tp16] rows of 64B; 16B-block bb stored at bb^((tp+c)&3)
// wl: z B-frags (gload_lds-staged, linear); zly: [n=t*32+i 256][18 shorts]
__global__ __launch_bounds__(256, 3) void kmain(const float* __restrict__ x,
                                                const float* __restrict__ b3,
                                                const float* __restrict__ bng,
                                                const float* __restrict__ bnb,
                                                const float* __restrict__ bnm,
                                                const float* __restrict__ bnv,
                                                const float* __restrict__ ws,
                                                float* __restrict__ out,
                                                float* __restrict__ lossP) {
  const int id   = blockIdx.x;                      // 0..31
  const int tile = ((id & 7) << 2) | (id >> 3);     // XCD-contiguous t-chunks
  const int b    = blockIdx.y;
  const int t0   = tile * 8;
  const int tid  = threadIdx.x;
  const int wid  = tid >> 6;
  const int lane = tid & 63;
  const int w4   = wid * 4;
  // z lane constants (32x32): n/col = lane&31, k-half = lane>>5
  const int col32 = lane & 31;
  const int half  = lane >> 5;
  const int t_l   = lane & 7;
  const int c_sl  = w4 + ((lane & 31) >> 3);
  // y lane constants (16x16)
  const int col16 = lane & 15;
  const int g     = (lane >> 4) & 3;

  __shared__ __align__(16) short wl[WL_SH];       // 18432 B
  __shared__ __align__(16) unsigned xw_u[4096];   // 16384 B
  __shared__ __align__(16) short zly[4608];       // 9216 B
  __shared__ float bnf[128];

  if (tid < 64) {
    float inv = bng[tid] / sqrtf(bnv[tid] + EPSV);
    bnf[tid] = inv;
    bnf[64 + tid] = (b3[tid] + b3[64 + tid] + b3[128 + tid] - bnm[tid]) * inv + bnb[tid];
  }

  const unsigned short* wpack = (const unsigned short*)((const char*)ws + WPACK_BYTE);
  const unsigned short* w3p   = (const unsigned short*)((const char*)ws + W3P_BYTE);

  auto stage_wl = [&](int s2) {
    const char* src = (const char*)(wpack + (size_t)(b * 3 + s2) * WL_SH);
#pragma unroll
    for (int j = 0; j < 5; ++j) {
      int off = j * 4096 + wid * 1024;
      if (off < WL_SH * 2) {
        __builtin_amdgcn_global_load_lds(
            (const __attribute__((address_space(1))) unsigned*)(src + off + lane * 16),
            (__attribute__((address_space(3))) unsigned*)((char*)wl + off + lane * 16),
            16, 0, 0);
      }
    }
  };

  auto stage_xw = [&](int p) {
    int c_s = tid >> 4, r = tid & 15;       // row tp = r
    int gt = t0 - 8 + r;
    int key = (r + c_s) & 3;
    unsigned hv[16];
    if (gt >= 0) {
      const float* rp = x + ((size_t)(b * 64 + p * 16 + c_s) * TDIM + gt) * VDIM;
      float f[25];
#pragma unroll
      for (int j = 0; j < 6; ++j) {
        float4 q4 = *(const float4*)(rp + j * 4);
        f[j * 4 + 0] = q4.x; f[j * 4 + 1] = q4.y;
        f[j * 4 + 2] = q4.z; f[j * 4 + 3] = q4.w;
      }
      f[24] = rp[24];
#pragma unroll
      for (int j = 0; j < 12; ++j) hv[j] = f2bf(f[2 * j]) | (f2bf(f[2 * j + 1]) << 16);
      hv[12] = f2bf(f[24]);
      hv[13] = 0; hv[14] = 0; hv[15] = 0;
    } else {
#pragma unroll
      for (int j = 0; j < 16; ++j) hv[j] = 0;
    }
    int rowb = (c_s * 16 + r) * 16;
#pragma unroll
    for (int bb = 0; bb < 4; ++bb) {
      uint4 wv; wv.x = hv[bb * 4]; wv.y = hv[bb * 4 + 1];
      wv.z = hv[bb * 4 + 2]; wv.w = hv[bb * 4 + 3];
      *(uint4*)&xw_u[rowb + ((bb ^ key) << 2)] = wv;
    }
  };

  const short* bs = wl + lane * 8;

  f4v yacc[4][4];
#pragma unroll
  for (int i = 0; i < 4; ++i)
#pragma unroll
    for (int j = 0; j < 4; ++j) yacc[i][j] = (f4v){0.f, 0.f, 0.f, 0.f};
  float lossA[3] = {0.f, 0.f, 0.f};

  stage_xw(0);
  stage_wl(0);

  for (int p = 0; p < 4; ++p) {
#pragma unroll
    for (int s = 0; s < 3; ++s) {
      __syncthreads();   // BARRIER_A: wl DMA + xw stores drained

      // y A-frags: issue now, latency hides under z; consumed after BARRIER_B
      const unsigned short* a3p = w3p + (size_t)(s * 4 + p) * 1024 + col16 * 16 + g * 4;
      s4v a3_0 = *(const s4v*)(a3p);
      s4v a3_1 = *(const s4v*)(a3p + 256);
      s4v a3_2 = *(const s4v*)(a3p + 512);
      s4v a3_3 = *(const s4v*)(a3p + 768);

      // ---- z MFMA: 18 x mfma_f32_32x32x16_bf16 per wave ----
      f16v za;
#pragma unroll
      for (int i = 0; i < 16; ++i) za[i] = 0.f;
#pragma unroll
      for (int k = 0; k < 9; ++k) {
        int tp = t_l + k;
        int key = (tp + c_sl) & 3;
        int rowb = (c_sl * 16 + tp) * 16;
#pragma unroll
        for (int vh = 0; vh < 2; ++vh) {
          int bb = vh * 2 + half;
          uint4 ua = *(const uint4*)&xw_u[rowb + ((bb ^ key) << 2)];
          s8v a = __builtin_bit_cast(s8v, ua);
          s8v bv = *(const s8v*)(bs + (k * 2 + vh) * 512);
          za = __builtin_amdgcn_mfma_f32_32x32x16_bf16(a, bv, za, 0, 0, 0);
        }
      }

      // ---- loss + zly (paired c writes) ----
      const short* xw_s = (const short*)xw_u;
      unsigned* zly_u32 = (unsigned*)zly;
      float lp = 0.f;
#pragma unroll
      for (int q4 = 0; q4 < 8; ++q4) {
        int q = (q4 & 3) | ((q4 & 4) << 1);     // reg pairs (q, q+4)
        int cl = w4 + ((q4 & 4) >> 1);          // c pair base: w4 or w4+2
        int t_rel = (q4 & 3) + 4 * half;
        float z0 = za[q], z1 = za[q + 4];
        int n = t_rel * 32 + col32;
        zly_u32[n * 9 + (cl >> 1)] = f2bf(z0) | (f2bf(z1) << 16);
        if (col32 < VDIM) {
          int tp = t_rel + 8;
          int bb = col32 >> 3;
          int i0 = (cl * 16 + tp) * 32 + ((bb ^ ((tp + cl) & 3)) << 3) + (col32 & 7);
          int i1 = ((cl + 1) * 16 + tp) * 32 + ((bb ^ ((tp + cl + 1) & 3)) << 3) + (col32 & 7);
          float d0 = z0 - bf2f((unsigned short)xw_s[i0]);
          float d1 = z1 - bf2f((unsigned short)xw_s[i1]);
          lp = fmaf(d0, d0, fmaf(d1, d1, lp));
        }
      }
      lossA[s] += lp;

      __syncthreads();   // BARRIER_B: zly ready; wl/xw reads done

      // ---- y MFMA: 16 x 16x16x16 per wave, K=16 c ----
      const unsigned* zly_u = (const unsigned*)zly;
#pragma unroll
      for (int u = 0; u < 4; ++u) {
        int n = (wid * 4 + u) * 16 + col16;
        int zo = n * 9 + g * 2;
        uint2 uz; uz.x = zly_u[zo]; uz.y = zly_u[zo + 1];
        s4v bz = __builtin_bit_cast(s4v, uz);
        yacc[0][u] = __builtin_amdgcn_mfma_f32_16x16x16bf16_1k(a3_0, bz, yacc[0][u], 0, 0, 0);
        yacc[1][u] = __builtin_amdgcn_mfma_f32_16x16x16bf16_1k(a3_1, bz, yacc[1][u], 0, 0, 0);
        yacc[2][u] = __builtin_amdgcn_mfma_f32_16x16x16bf16_1k(a3_2, bz, yacc[2][u], 0, 0, 0);
        yacc[3][u] = __builtin_amdgcn_mfma_f32_16x16x16bf16_1k(a3_3, bz, yacc[3][u], 0, 0, 0);
      }

      // stage next buffers in the y shadow (all wl/xw reads complete)
      if (s < 2) {
        stage_wl(s + 1);
      } else if (p < 3) {
        stage_wl(0);
        stage_xw(p + 1);
      }
    }
  }

  __syncthreads();

  // ---- loss reduce (xw region as scratch) ----
  {
    float* redf = (float*)xw_u;
#pragma unroll
    for (int s = 0; s < 3; ++s) {
      redf[tid] = lossA[s];
      __syncthreads();
      for (int st = 128; st > 0; st >>= 1) {
        if (tid < st) redf[tid] += redf[tid + st];
        __syncthreads();
      }
      if (tid == 0) lossP[(b * 32 + id) * 3 + s] = redf[0];
      __syncthreads();
    }
  }

  // ---- epilogue: y = relu(acc*inv + off + x) ----
#pragma unroll
  for (int u = 0; u < 4; ++u) {
    int n = (wid * 4 + u) * 16 + col16;
    int t_out = n >> 5, i = n & 31;
    if (i < VDIM) {
      int gt = t0 + t_out;
#pragma unroll
      for (int mt = 0; mt < 4; ++mt) {
#pragma unroll
        for (int q = 0; q < 4; ++q) {
          int o = mt * 16 + g * 4 + q;
          size_t idx = ((size_t)(b * 64 + o) * TDIM + gt) * VDIM + i;
          float v = yacc[mt][u][q] * bnf[o] + bnf[64 + o] + x[idx];
          out[idx] = fmaxf(v, 0.f);
        }
      }
    }
  }
}

// ---------------- Kernel 4: finalize loss ----------------
__global__ __launch_bounds__(256) void kfin(const float* __restrict__ lossP,
                                            float* __restrict__ out_loss) {
  __shared__ float red[256];
  int tid = threadIdx.x;
  for (int s = 0; s < 3; ++s) {
    float a = 0.f;
    for (int i = tid; i < 1024; i += 256) a += lossP[i * 3 + s];
    red[tid] = a;
    __syncthreads();
    for (int st = 128; st > 0; st >>= 1) {
      if (tid < st) red[tid] += red[tid + st];
      __syncthreads();
    }
    if (tid == 0) out_loss[s] = red[0] * (1.f / 13107200.f);
    __syncthreads();
  }
}

extern "C" void kernel_launch(void* const* d_in, const int* in_sizes, int n_in,
                              void* d_out, int out_size, void* d_ws, size_t ws_size,
                              hipStream_t stream) {
  (void)in_sizes; (void)n_in; (void)out_size; (void)ws_size;
  const float* x     = (const float*)d_in[0];
  const float* A     = (const float*)d_in[1];
  const float* alpha = (const float*)d_in[2];
  const float* W1    = (const float*)d_in[3];
  const float* b1    = (const float*)d_in[4];
  const float* W2    = (const float*)d_in[5];
  const float* b2    = (const float*)d_in[6];
  const float* W3    = (const float*)d_in[7];
  const float* b3    = (const float*)d_in[8];
  const float* bng   = (const float*)d_in[9];
  const float* bnb   = (const float*)d_in[10];
  const float* bnm   = (const float*)d_in[11];
  const float* bnv   = (const float*)d_in[12];
  float* out = (float*)d_out;
  float* ws  = (float*)d_ws;
  float* out_loss  = out + 13107200;
  float* out_ridge = out + 13107203;
  float* lossP = ws + LOSSP_OFF;

  kmean<<<2048, 256, 0, stream>>>(x, ws);
  kadj<<<96, 256, 0, stream>>>(A, alpha, W1, b1, W2, b2, W3, ws, out_ridge);
  kmain<<<dim3(32, 32), 256, 0, stream>>>(x, b3, bng, bnb, bnm, bnv, ws, out, lossP);
  kfin<<<1, 256, 0, stream>>>(lossP, out_loss);
}

// Round 11
// 145.862 us; speedup vs baseline: 4.4000x; 1.0169x over previous
//
#include <hip/hip_runtime.h>
#include <hip/hip_bf16.h>

#define TDIM 256
#define VDIM 25
#define CDIM 64
#define BDIM 32
#define EPSV 1e-5f

// ws layout
#define XM_OFF     0            // 51200 floats
#define LOSSP_OFF  51200        // 3072 floats (1024 blocks * 3)
#define WPACK_BYTE 229376       // 96 packs * 9216 shorts (bf16 z B-frags, 32x32x16)
#define WL_SH      9216         // shorts per (b,s): 18 kk * (2 hf * 32 n * 8 j)
#define W3P_BYTE   (WPACK_BYTE + 96 * WL_SH * 2)  // 3s*4096 shorts (y A-frags, 16x16x16)

typedef short s4v __attribute__((ext_vector_type(4)));
typedef short s8v __attribute__((ext_vector_type(8)));
typedef float f4v __attribute__((ext_vector_type(4)));
typedef float f16v __attribute__((ext_vector_type(16)));

__device__ __forceinline__ unsigned f2bf(float f) {
  __hip_bfloat16 h = __float2bfloat16(f);
  return (unsigned)__builtin_bit_cast(unsigned short, h);
}
__device__ __forceinline__ float bf2f(unsigned short u) {
  unsigned v = ((unsigned)u) << 16;
  return __builtin_bit_cast(float, v);
}

// raw barrier, no waitcnt drain (BZ): sync wave arrival only
#define BARRIER_RAW() do {                        \
  asm volatile("" ::: "memory");                  \
  __builtin_amdgcn_sched_barrier(0);              \
  __builtin_amdgcn_s_barrier();                   \
  __builtin_amdgcn_sched_barrier(0);              \
  asm volatile("" ::: "memory");                  \
} while (0)

// barrier with LDS-only drain (BB): ds writes visible, vmem (DMA) stays in flight
#define BARRIER_LDS() do {                        \
  __builtin_amdgcn_sched_barrier(0);              \
  asm volatile("s_waitcnt lgkmcnt(0)" ::: "memory"); \
  __builtin_amdgcn_s_barrier();                   \
  __builtin_amdgcn_sched_barrier(0);              \
  asm volatile("" ::: "memory");                  \
} while (0)

// ---------------- Kernel 1: xm[b,c,v] = mean over T ----------------
__global__ __launch_bounds__(256) void kmean(const float* __restrict__ x,
                                             float* __restrict__ ws) {
  int bc = blockIdx.x;
  int tid = threadIdx.x;
  int vl = tid & 31, tr = tid >> 5;
  float acc = 0.f;
  if (vl < VDIM) {
    const float* p = x + (size_t)bc * TDIM * VDIM + vl;
    for (int t = tr; t < TDIM; t += 8) acc += p[(size_t)t * VDIM];
  }
  __shared__ float red[256];
  red[tid] = acc;
  __syncthreads();
  if (tr == 0 && vl < VDIM) {
    float s = 0.f;
    for (int r = 0; r < 8; ++r) s += red[r * 32 + vl];
    ws[XM_OFF + bc * VDIM + vl] = s * (1.f / 256.f);
  }
}

// ---------------- Kernel 2: dynamic weights -> packed bf16 fragments ----------------
__global__ __launch_bounds__(256) void kadj(const float* __restrict__ A,
                                            const float* __restrict__ alpha,
                                            const float* __restrict__ W1,
                                            const float* __restrict__ b1,
                                            const float* __restrict__ W2,
                                            const float* __restrict__ b2,
                                            const float* __restrict__ W3,
                                            float* __restrict__ ws,
                                            float* __restrict__ out_ridge) {
  int s = blockIdx.x >> 5, b = blockIdx.x & 31;
  int tid = threadIdx.x;
  __shared__ float xm[CDIM * VDIM];
  __shared__ float w1l[9 * CDIM], w2l[9 * CDIM];
  __shared__ float b1l[9], b2l[9];
  __shared__ float x1l[9 * VDIM], x2l[9 * VDIM];
  __shared__ float red[256];
  __shared__ float wsm[9 * VDIM * VDIM];   // w[k][v][i] f32

  for (int i = tid; i < CDIM * VDIM; i += 256) xm[i] = ws[XM_OFF + b * CDIM * VDIM + i];
  for (int i = tid; i < 9 * CDIM; i += 256) {
    w1l[i] = W1[s * 9 * CDIM + i];
    w2l[i] = W2[s * 9 * CDIM + i];
  }
  if (tid < 9) { b1l[tid] = b1[s * 9 + tid]; b2l[tid] = b2[s * 9 + tid]; }
  __syncthreads();

  if (tid < 9 * VDIM) {
    int ts = tid / VDIM, v = tid % VDIM;
    float a1 = 0.f, a2 = 0.f;
    for (int c = 0; c < CDIM; ++c) {
      float xv = xm[c * VDIM + v];
      a1 = fmaf(xv, w1l[ts * CDIM + c], a1);
      a2 = fmaf(xv, w2l[ts * CDIM + c], a2);
    }
    x1l[tid] = a1 + b1l[ts];
    x2l[tid] = a2 + b2l[ts];
  }
  __syncthreads();

  float al = alpha[0];
  float rid = 0.f;
  for (int idx = tid; idx < 9 * VDIM * VDIM; idx += 256) {
    int k = idx / (VDIM * VDIM);
    int r = (idx / VDIM) % VDIM;   // v
    int q = idx % VDIM;            // i
    float adj = tanhf(x1l[k * VDIM + r] - x2l[k * VDIM + q]);
    rid += adj * adj;
    wsm[idx] = fmaf(adj, al, A[(s * VDIM + r) * VDIM + q]);
  }
  red[tid] = rid;
  __syncthreads();   // wsm + red complete

  // pack z B-frags for 32x32x16: [kk 18][hf 2][n 32][j 8]
  // lane l reads its 8 shorts at wl + l*8:  l*8+j == hf*256 + n*8 + j  (hf=l>>5, n=l&31)
  {
    unsigned short* wp = (unsigned short*)((char*)ws + WPACK_BYTE) + (size_t)(b * 3 + s) * WL_SH;
    for (int idx = tid; idx < WL_SH; idx += 256) {
      int kk = idx >> 9;           // 0..17
      int rem = idx & 511;
      int hf = rem >> 8;           // 0..1
      int n = (rem >> 3) & 31;     // i
      int j = rem & 7;
      int k = kk >> 1, vh = kk & 1;
      int v = vh * 16 + hf * 8 + j;
      float val = (v < VDIM && n < VDIM) ? wsm[(k * VDIM + v) * VDIM + n] : 0.f;
      wp[idx] = (unsigned short)f2bf(val);
    }
  }

  for (int st = 128; st > 0; st >>= 1) {
    if (tid < st) red[tid] += red[tid + st];
    __syncthreads();
  }
  if (tid == 0) out_ridge[s * BDIM + b] = red[0];

  // pack W3 A-frags (16x16x16): [s][p][mt][col16][g4][j4]
  if (b == 0) {
    unsigned short* w3p = (unsigned short*)((char*)ws + W3P_BYTE) + s * 4096;
    for (int idx = tid; idx < 4096; idx += 256) {
      int pm = idx >> 8;          // p*4+mt
      int p = pm >> 2, mt = pm & 3;
      int e = idx & 255;
      int colv = e >> 4, gg = (e >> 2) & 3, jj = e & 3;
      int o = mt * 16 + colv, c = p * 16 + gg * 4 + jj;
      w3p[idx] = (unsigned short)f2bf(W3[(s * CDIM + o) * CDIM + c]);
    }
  }
}

// ---------------- Kernel 3: fused z(32x32 MFMA) -> (loss, y(16x16)), t-tile = 8 ----------------
// Phase: z | BZ(raw) | DMA-issue next wl | loss->zly | BB(lgkm) | y | syncthreads(full drain)
__global__ __launch_bounds__(256, 3) void kmain(const float* __restrict__ x,
                                                const float* __restrict__ b3,
                                                const float* __restrict__ bng,
                                                const float* __restrict__ bnb,
                                                const float* __restrict__ bnm,
                                                const float* __restrict__ bnv,
                                                const float* __restrict__ ws,
                                                float* __restrict__ out,
                                                float* __restrict__ lossP) {
  const int id   = blockIdx.x;                      // 0..31
  const int tile = ((id & 7) << 2) | (id >> 3);     // XCD-contiguous t-chunks
  const int b    = blockIdx.y;
  const int t0   = tile * 8;
  const int tid  = threadIdx.x;
  const int wid  = tid >> 6;
  const int lane = tid & 63;
  const int w4   = wid * 4;
  // z lane constants (32x32)
  const int col32 = lane & 31;
  const int half  = lane >> 5;
  const int t_l   = lane & 7;
  const int c_sl  = w4 + ((lane & 31) >> 3);
  // y lane constants (16x16)
  const int col16 = lane & 15;
  const int g     = (lane >> 4) & 3;

  __shared__ __align__(16) short wl[WL_SH];       // 18432 B
  __shared__ __align__(16) unsigned xw_u[4096];   // 16384 B
  __shared__ __align__(16) short zly[4608];       // 9216 B
  __shared__ float bnf[128];

  if (tid < 64) {
    float inv = bng[tid] / sqrtf(bnv[tid] + EPSV);
    bnf[tid] = inv;
    bnf[64 + tid] = (b3[tid] + b3[64 + tid] + b3[128 + tid] - bnm[tid]) * inv + bnb[tid];
  }

  const unsigned short* wpack = (const unsigned short*)((const char*)ws + WPACK_BYTE);
  const unsigned short* w3p   = (const unsigned short*)((const char*)ws + W3P_BYTE);

  auto stage_wl = [&](int s2) {
    const char* src = (const char*)(wpack + (size_t)(b * 3 + s2) * WL_SH);
#pragma unroll
    for (int j = 0; j < 5; ++j) {
      int off = j * 4096 + wid * 1024;
      if (off < WL_SH * 2) {
        __builtin_amdgcn_global_load_lds(
            (const __attribute__((address_space(1))) unsigned*)(src + off + lane * 16),
            (__attribute__((address_space(3))) unsigned*)((char*)wl + off + lane * 16),
            16, 0, 0);
      }
    }
  };

  auto stage_xw = [&](int p) {
    int c_s = tid >> 4, r = tid & 15;       // row tp = r
    int gt = t0 - 8 + r;
    int key = (r + c_s) & 3;
    unsigned hv[16];
    if (gt >= 0) {
      const float* rp = x + ((size_t)(b * 64 + p * 16 + c_s) * TDIM + gt) * VDIM;
      float f[25];
#pragma unroll
      for (int j = 0; j < 6; ++j) {
        float4 q4 = *(const float4*)(rp + j * 4);
        f[j * 4 + 0] = q4.x; f[j * 4 + 1] = q4.y;
        f[j * 4 + 2] = q4.z; f[j * 4 + 3] = q4.w;
      }
      f[24] = rp[24];
#pragma unroll
      for (int j = 0; j < 12; ++j) hv[j] = f2bf(f[2 * j]) | (f2bf(f[2 * j + 1]) << 16);
      hv[12] = f2bf(f[24]);
      hv[13] = 0; hv[14] = 0; hv[15] = 0;
    } else {
#pragma unroll
      for (int j = 0; j < 16; ++j) hv[j] = 0;
    }
    int rowb = (c_s * 16 + r) * 16;
#pragma unroll
    for (int bb = 0; bb < 4; ++bb) {
      uint4 wv; wv.x = hv[bb * 4]; wv.y = hv[bb * 4 + 1];
      wv.z = hv[bb * 4 + 2]; wv.w = hv[bb * 4 + 3];
      *(uint4*)&xw_u[rowb + ((bb ^ key) << 2)] = wv;
    }
  };

  const short* bs = wl + lane * 8;

  f4v yacc[4][4];
#pragma unroll
  for (int i = 0; i < 4; ++i)
#pragma unroll
    for (int j = 0; j < 4; ++j) yacc[i][j] = (f4v){0.f, 0.f, 0.f, 0.f};
  float lossA[3] = {0.f, 0.f, 0.f};

  stage_xw(0);
  stage_wl(0);
  __syncthreads();   // initial: wl DMA + xw stores drained

  for (int p = 0; p < 4; ++p) {
#pragma unroll
    for (int s = 0; s < 3; ++s) {
      // y A-frags: issue now, consumed after BB (compiler keeps counted vmcnt)
      const unsigned short* a3p = w3p + (size_t)(s * 4 + p) * 1024 + col16 * 16 + g * 4;
      s4v a3_0 = *(const s4v*)(a3p);
      s4v a3_1 = *(const s4v*)(a3p + 256);
      s4v a3_2 = *(const s4v*)(a3p + 512);
      s4v a3_3 = *(const s4v*)(a3p + 768);

      // ---- z MFMA: 18 x mfma_f32_32x32x16_bf16 per wave ----
      f16v za;
#pragma unroll
      for (int i = 0; i < 16; ++i) za[i] = 0.f;
#pragma unroll
      for (int k = 0; k < 9; ++k) {
        int tp = t_l + k;
        int key = (tp + c_sl) & 3;
        int rowb = (c_sl * 16 + tp) * 16;
#pragma unroll
        for (int vh = 0; vh < 2; ++vh) {
          int bb = vh * 2 + half;
          uint4 ua = *(const uint4*)&xw_u[rowb + ((bb ^ key) << 2)];
          s8v a = __builtin_bit_cast(s8v, ua);
          s8v bv = *(const s8v*)(bs + (k * 2 + vh) * 512);
          za = __builtin_amdgcn_mfma_f32_32x32x16_bf16(a, bv, za, 0, 0, 0);
        }
      }

      BARRIER_RAW();   // BZ: every wave's wl reads are complete (no drain needed)

      // issue next wl DMA — has loss+BB+y to land before the full drain
      if (!(p == 3 && s == 2)) stage_wl(s < 2 ? s + 1 : 0);

      // ---- loss + zly (paired c writes) ----
      const short* xw_s = (const short*)xw_u;
      unsigned* zly_u32 = (unsigned*)zly;
      float lp = 0.f;
#pragma unroll
      for (int q4 = 0; q4 < 8; ++q4) {
        int q = (q4 & 3) | ((q4 & 4) << 1);     // reg pairs (q, q+4)
        int cl = w4 + ((q4 & 4) >> 1);          // c pair base: w4 or w4+2
        int t_rel = (q4 & 3) + 4 * half;
        float z0 = za[q], z1 = za[q + 4];
        int n = t_rel * 32 + col32;
        zly_u32[n * 9 + (cl >> 1)] = f2bf(z0) | (f2bf(z1) << 16);
        if (col32 < VDIM) {
          int tp = t_rel + 8;
          int bb = col32 >> 3;
          int i0 = (cl * 16 + tp) * 32 + ((bb ^ ((tp + cl) & 3)) << 3) + (col32 & 7);
          int i1 = ((cl + 1) * 16 + tp) * 32 + ((bb ^ ((tp + cl + 1) & 3)) << 3) + (col32 & 7);
          float d0 = z0 - bf2f((unsigned short)xw_s[i0]);
          float d1 = z1 - bf2f((unsigned short)xw_s[i1]);
          lp = fmaf(d0, d0, fmaf(d1, d1, lp));
        }
      }
      lossA[s] += lp;

      BARRIER_LDS();   // BB: zly visible; wl DMA stays in flight

      // ---- y MFMA: 16 x 16x16x16 per wave, K=16 c ----
      const unsigned* zly_u = (const unsigned*)zly;
#pragma unroll
      for (int u = 0; u < 4; ++u) {
        int n = (wid * 4 + u) * 16 + col16;
        int zo = n * 9 + g * 2;
        uint2 uz; uz.x = zly_u[zo]; uz.y = zly_u[zo + 1];
        s4v bz = __builtin_bit_cast(s4v, uz);
        yacc[0][u] = __builtin_amdgcn_mfma_f32_16x16x16bf16_1k(a3_0, bz, yacc[0][u], 0, 0, 0);
        yacc[1][u] = __builtin_amdgcn_mfma_f32_16x16x16bf16_1k(a3_1, bz, yacc[1][u], 0, 0, 0);
        yacc[2][u] = __builtin_amdgcn_mfma_f32_16x16x16bf16_1k(a3_2, bz, yacc[2][u], 0, 0, 0);
        yacc[3][u] = __builtin_amdgcn_mfma_f32_16x16x16bf16_1k(a3_3, bz, yacc[3][u], 0, 0, 0);
      }

      // stage next c-panel (xw reads done at BB; zly untouched)
      if (s == 2 && p < 3) stage_xw(p + 1);

      __syncthreads();   // full drain: wl DMA landed, xw ds_writes visible, zly reads done
    }
  }

  // ---- loss reduce (xw region as scratch) ----
  {
    float* redf = (float*)xw_u;
#pragma unroll
    for (int s = 0; s < 3; ++s) {
      redf[tid] = lossA[s];
      __syncthreads();
      for (int st = 128; st > 0; st >>= 1) {
        if (tid < st) redf[tid] += redf[tid + st];
        __syncthreads();
      }
      if (tid == 0) lossP[(b * 32 + id) * 3 + s] = redf[0];
      __syncthreads();
    }
  }

  // ---- epilogue: y = relu(acc*inv + off + x) ----
#pragma unroll
  for (int u = 0; u < 4; ++u) {
    int n = (wid * 4 + u) * 16 + col16;
    int t_out = n >> 5, i = n & 31;
    if (i < VDIM) {
      int gt = t0 + t_out;
#pragma unroll
      for (int mt = 0; mt < 4; ++mt) {
#pragma unroll
        for (int q = 0; q < 4; ++q) {
          int o = mt * 16 + g * 4 + q;
          size_t idx = ((size_t)(b * 64 + o) * TDIM + gt) * VDIM + i;
          float v = yacc[mt][u][q] * bnf[o] + bnf[64 + o] + x[idx];
          out[idx] = fmaxf(v, 0.f);
        }
      }
    }
  }
}

// ---------------- Kernel 4: finalize loss ----------------
__global__ __launch_bounds__(256) void kfin(const float* __restrict__ lossP,
                                            float* __restrict__ out_loss) {
  __shared__ float red[256];
  int tid = threadIdx.x;
  for (int s = 0; s < 3; ++s) {
    float a = 0.f;
    for (int i = tid; i < 1024; i += 256) a += lossP[i * 3 + s];
    red[tid] = a;
    __syncthreads();
    for (int st = 128; st > 0; st >>= 1) {
      if (tid < st) red[tid] += red[tid + st];
      __syncthreads();
    }
    if (tid == 0) out_loss[s] = red[0] * (1.f / 13107200.f);
    __syncthreads();
  }
}

extern "C" void kernel_launch(void* const* d_in, const int* in_sizes, int n_in,
                              void* d_out, int out_size, void* d_ws, size_t ws_size,
                              hipStream_t stream) {
  (void)in_sizes; (void)n_in; (void)out_size; (void)ws_size;
  const float* x     = (const float*)d_in[0];
  const float* A     = (const float*)d_in[1];
  const float* alpha = (const float*)d_in[2];
  const float* W1    = (const float*)d_in[3];
  const float* b1    = (const float*)d_in[4];
  const float* W2    = (const float*)d_in[5];
  const float* b2    = (const float*)d_in[6];
  const float* W3    = (const float*)d_in[7];
  const float* b3    = (const float*)d_in[8];
  const float* bng   = (const float*)d_in[9];
  const float* bnb   = (const float*)d_in[10];
  const float* bnm   = (const float*)d_in[11];
  const float* bnv   = (const float*)d_in[12];
  float* out = (float*)d_out;
  float* ws  = (float*)d_ws;
  float* out_loss  = out + 13107200;
  float* out_ridge = out + 13107203;
  float* lossP = ws + LOSSP_OFF;

  kmean<<<2048, 256, 0, stream>>>(x, ws);
  kadj<<<96, 256, 0, stream>>>(A, alpha, W1, b1, W2, b2, W3, ws, out_ridge);
  kmain<<<dim3(32, 32), 256, 0, stream>>>(x, b3, bng, bnb, bnm, bnv, ws, out, lossP);
  kfin<<<1, 256, 0, stream>>>(lossP, out_loss);
}